// Round 1
// baseline (447.080 us; speedup 1.0000x reference)
//
#include <hip/hip_runtime.h>
#include <stdint.h>

// B=8, N=4096, C=768, H=8, hd=96. bf16 MFMA path.
// LDS tiles are row-major [rows][8 chunks of 8 elem] with XOR chunk swizzle:
// LDS slot (row, c) holds global chunk c ^ (row&7)  -> conflict-free ds_read_b128
// while global_load_lds staging stays contiguous (lanes permute within a 128B row).

typedef __attribute__((ext_vector_type(8))) __bf16 bf16x8;
typedef __attribute__((ext_vector_type(4))) float f32x4;

__device__ __forceinline__ unsigned short f2b(float f) {
  uint32_t u = __float_as_uint(f);
  u += 0x7FFF + ((u >> 16) & 1);
  return (unsigned short)(u >> 16);
}

__device__ __forceinline__ void gload16(const void* g, void* l) {
  __builtin_amdgcn_global_load_lds(
      (__attribute__((address_space(1))) void*)(uintptr_t)g,
      (__attribute__((address_space(3))) void*)(uintptr_t)l, 16, 0, 0);
}

// ---------------- conversions + zero S/normsq ----------------
__global__ void cvt_bf16(const float* __restrict__ in, unsigned short* __restrict__ out, int n4,
                         float* __restrict__ Z, int nz4) {
  int gid = blockIdx.x * blockDim.x + threadIdx.x;
  if (gid < nz4) reinterpret_cast<float4*>(Z)[gid] = make_float4(0.f, 0.f, 0.f, 0.f);
  int stride = gridDim.x * blockDim.x;
  for (int i = gid; i < n4; i += stride) {
    float4 v = reinterpret_cast<const float4*>(in)[i];
    ushort4 o;
    o.x = f2b(v.x); o.y = f2b(v.y); o.z = f2b(v.z); o.w = f2b(v.w);
    reinterpret_cast<ushort4*>(out)[i] = o;
  }
}

__global__ void cvt_transpose(const float* __restrict__ in, unsigned short* __restrict__ out,
                              int K, int NC) {
  __shared__ float tile[32][33];
  int bx = blockIdx.x, by = blockIdx.y;
  int tx = threadIdx.x & 31, ty = threadIdx.x >> 5;
  for (int r = ty; r < 32; r += 8)
    tile[r][tx] = in[(size_t)(by * 32 + r) * NC + bx * 32 + tx];
  __syncthreads();
  for (int r = ty; r < 32; r += 8)
    out[(size_t)(bx * 32 + r) * K + by * 32 + tx] = f2b(tile[tx][r]);
}

// ---------------- GEMM1: qkv = x @ Wqkv, scatter + fused norm^2 ----------------
// qkT: [2][64 bh][96 d][4096 n]; vT: [64 bh][4096 n][96 e]; normsq: [2][64][96]
__global__ __launch_bounds__(256, 2) void gemm_qkv(
    const unsigned short* __restrict__ A, const unsigned short* __restrict__ Bt,
    unsigned short* __restrict__ qkT, unsigned short* __restrict__ vT,
    float* __restrict__ normsq) {
  __shared__ __align__(16) unsigned short lds[17408];  // As[128][64]@0, Bs@8192; bounce [128][136]
  int bj = blockIdx.x;                        // 0..17
  int bm = blockIdx.y;                        // 0..255
  int m0 = bm * 128, j0 = bj * 128;
  int tid = threadIdx.x;
  int wid = tid >> 6, lane = tid & 63;
  int wm = wid >> 1, wn = wid & 1;
  int quad = lane >> 4, l16 = lane & 15;
  int srow = lane >> 3, sch = lane & 7;       // staging: 8 rows x 8 chunks per instr
  int cmem = sch ^ srow;                      // swizzled chunk to fetch

  f32x4 acc[4][4];
  f32x4 z = {0.f, 0.f, 0.f, 0.f};
#pragma unroll
  for (int i = 0; i < 4; i++)
#pragma unroll
    for (int j = 0; j < 4; j++) acc[i][j] = z;

  const unsigned short* Ab = A + (size_t)m0 * 768;
  const unsigned short* Bb = Bt + (size_t)j0 * 768;

  for (int k0 = 0; k0 < 768; k0 += 64) {
#pragma unroll
    for (int i = 0; i < 4; i++) {
      int ig = wid * 4 + i;                   // 0..15, 8 rows each
      int row = ig * 8 + srow;
      gload16(Ab + (size_t)row * 768 + k0 + cmem * 8, &lds[ig * 512]);
      gload16(Bb + (size_t)row * 768 + k0 + cmem * 8, &lds[8192 + ig * 512]);
    }
    __syncthreads();
#pragma unroll
    for (int kk = 0; kk < 2; kk++) {
      int cs = ((kk * 4 + quad) ^ (l16 & 7)) * 8;
      bf16x8 af[4], bfr[4];
#pragma unroll
      for (int mi = 0; mi < 4; mi++)
        af[mi] = *(const bf16x8*)&lds[(wm * 64 + mi * 16 + l16) * 64 + cs];
#pragma unroll
      for (int ni = 0; ni < 4; ni++)
        bfr[ni] = *(const bf16x8*)&lds[8192 + (wn * 64 + ni * 16 + l16) * 64 + cs];
#pragma unroll
      for (int mi = 0; mi < 4; mi++)
#pragma unroll
        for (int ni = 0; ni < 4; ni++)
          acc[mi][ni] = __builtin_amdgcn_mfma_f32_16x16x32_bf16(af[mi], bfr[ni], acc[mi][ni], 0, 0, 0);
    }
    __syncthreads();
  }

  int s = bj / 6;                  // 0=q,1=k,2=v
  int b = bm >> 5;
  int n0 = m0 & 4095;
  bool isv = (s == 2);

  // fused norm^2 accumulation for q/k (fp32, pre-rounding)
  if (!isv) {
#pragma unroll
    for (int ni = 0; ni < 4; ni++) {
      float ss = 0.f;
#pragma unroll
      for (int mi = 0; mi < 4; mi++)
#pragma unroll
        for (int r = 0; r < 4; r++) ss += acc[mi][ni][r] * acc[mi][ni][r];
      ss += __shfl_down(ss, 32, 64);
      ss += __shfl_down(ss, 16, 64);
      if (lane < 16) {
        int cc = wn * 64 + ni * 16 + l16;
        int local = j0 + cc - s * 768;
        int hh = local / 96, d = local - hh * 96;
        atomicAdd(&normsq[s * 6144 + (b * 8 + hh) * 96 + d], ss);
      }
    }
  }

  // bounce (padded stride 136 -> no bank conflicts)
#pragma unroll
  for (int mi = 0; mi < 4; mi++)
#pragma unroll
    for (int ni = 0; ni < 4; ni++)
#pragma unroll
      for (int r = 0; r < 4; r++) {
        int m = wm * 64 + mi * 16 + quad * 4 + r;
        int cc = wn * 64 + ni * 16 + l16;
        unsigned short v = f2b(acc[mi][ni][r]);
        lds[isv ? (m * 136 + cc) : (cc * 136 + m)] = v;
      }
  __syncthreads();
  if (!isv) {
#pragma unroll
    for (int it = 0; it < 8; it++) {
      int id = tid + it * 256;
      int jr = id >> 4, mc = id & 15;
      int j = j0 + jr;
      int hh = (j - s * 768) / 96;
      int d = j - s * 768 - hh * 96;
      size_t off = ((size_t)(s * 64 + b * 8 + hh) * 96 + d) * 4096 + n0 + mc * 8;
      *(uint4*)&qkT[off] = *(const uint4*)&lds[jr * 136 + mc * 8];
    }
  } else {
#pragma unroll
    for (int it = 0; it < 8; it++) {
      int id = tid + it * 256;
      int mr = id >> 4, ch = id & 15;
      int cp = (j0 - 1536) + ch * 8;
      int hh = cp / 96, e = cp - hh * 96;
      size_t off = ((size_t)(b * 8 + hh) * 4096 + (n0 + mr)) * 96 + e;
      *(uint4*)&vT[off] = *(const uint4*)&lds[mr * 136 + ch * 8];
    }
  }
}

// ---------------- split-K S = q @ k^T ----------------
__global__ __launch_bounds__(256, 2) void attn_s(const unsigned short* __restrict__ qkT,
                                                 float* __restrict__ S) {
  __shared__ __align__(16) unsigned short lds[12288];  // qs[96][64]@0, ks@6144 (swizzled)
  int blk = blockIdx.x;
  int bh = blk >> 3, ks = blk & 7;
  const unsigned short* qb = qkT + (size_t)bh * 96 * 4096;
  const unsigned short* kb = qkT + (size_t)(64 + bh) * 96 * 4096;
  int tid = threadIdx.x, wid = tid >> 6, lane = tid & 63;
  int wm = wid >> 1, wn = wid & 1, quad = lane >> 4, l16 = lane & 15;
  int srow = lane >> 3, sch = lane & 7;
  int cmem = sch ^ srow;
  f32x4 acc[3][3];
  f32x4 z = {0.f, 0.f, 0.f, 0.f};
#pragma unroll
  for (int i = 0; i < 3; i++)
#pragma unroll
    for (int j = 0; j < 3; j++) acc[i][j] = z;

  for (int k0 = ks * 512; k0 < ks * 512 + 512; k0 += 64) {
#pragma unroll
    for (int i = 0; i < 3; i++) {
      int ig = wid * 3 + i;                  // 0..11, 8 rows each
      int row = ig * 8 + srow;
      gload16(qb + (size_t)row * 4096 + k0 + cmem * 8, &lds[ig * 512]);
      gload16(kb + (size_t)row * 4096 + k0 + cmem * 8, &lds[6144 + ig * 512]);
    }
    __syncthreads();
#pragma unroll
    for (int kk = 0; kk < 2; kk++) {
      int cs = ((kk * 4 + quad) ^ (l16 & 7)) * 8;
      bf16x8 af[3], bfr[3];
#pragma unroll
      for (int mi = 0; mi < 3; mi++)
        af[mi] = *(const bf16x8*)&lds[(wm * 48 + mi * 16 + l16) * 64 + cs];
#pragma unroll
      for (int ni = 0; ni < 3; ni++)
        bfr[ni] = *(const bf16x8*)&lds[6144 + (wn * 48 + ni * 16 + l16) * 64 + cs];
#pragma unroll
      for (int mi = 0; mi < 3; mi++)
#pragma unroll
        for (int ni = 0; ni < 3; ni++)
          acc[mi][ni] = __builtin_amdgcn_mfma_f32_16x16x32_bf16(af[mi], bfr[ni], acc[mi][ni], 0, 0, 0);
    }
    __syncthreads();
  }
  float* Sb = S + (size_t)bh * 9216;
#pragma unroll
  for (int mi = 0; mi < 3; mi++)
#pragma unroll
    for (int ni = 0; ni < 3; ni++)
#pragma unroll
      for (int r = 0; r < 4; r++)
        atomicAdd(&Sb[(wm * 48 + mi * 16 + quad * 4 + r) * 96 + wn * 48 + ni * 16 + l16],
                  acc[mi][ni][r]);
}

// ---------------- softmax (once per bh): attnB = softmax(S*iq*ik) as bf16 [64][96][104] ----------------
__global__ __launch_bounds__(128) void softmax96(
    const float* __restrict__ S, const float* __restrict__ normsq,
    const float* __restrict__ temp, unsigned short* __restrict__ attnB) {
  __shared__ float ik[96];
  int bh = blockIdx.x;              // 0..63
  int h = bh & 7;
  int tid = threadIdx.x;
  if (tid < 96) ik[tid] = 1.0f / fmaxf(sqrtf(normsq[6144 + bh * 96 + tid]), 1e-12f);
  __syncthreads();
  if (tid < 96) {
    int d = tid;
    const float* Srow = S + (size_t)bh * 9216 + d * 96;
    float iq = (1.0f / fmaxf(sqrtf(normsq[bh * 96 + d]), 1e-12f)) * temp[h];
    float mx = -1e30f;
    for (int e = 0; e < 96; e++) mx = fmaxf(mx, Srow[e] * iq * ik[e]);
    float sum = 0.f;
    for (int e = 0; e < 96; e++) sum += __expf(Srow[e] * iq * ik[e] - mx);
    float inv = 1.0f / sum;
    unsigned short* row = attnB + (size_t)bh * 9984 + d * 104;
    for (int e = 0; e < 96; e++) row[e] = f2b(__expf(Srow[e] * iq * ik[e] - mx) * inv);
    for (int e = 96; e < 104; e++) row[e] = 0;  // pad chunk (never consumed by MFMA)
  }
}

// ---------------- out = attn @ v (attn pre-softmaxed) ----------------
__global__ __launch_bounds__(256, 2) void attn_v(
    const unsigned short* __restrict__ attnB, const unsigned short* __restrict__ vT,
    unsigned short* __restrict__ U) {
  // attn [96][104]@0 (padded dest region 10240), vs [128][13 chunks][8]@10240 (13312)
  __shared__ __align__(16) unsigned short lds[23552];
  int blk = blockIdx.x;
  int bh = blk >> 5, nc = blk & 31;
  int b = bh >> 3, h = bh & 7;
  int n0 = nc * 128;
  int tid = threadIdx.x, wid = tid >> 6, lane = tid & 63;
  int wm = wid >> 1, wn = wid & 1, quad = lane >> 4, l16 = lane & 15;

  // stage attn [96][104]: 1248 16B chunks, contiguous in global AND lds (stride 104 = 13 chunks).
  // Loop runs 1280 chunks (wave-aligned); tail chunks clamp source and land in the pad
  // region [9984,10240) so they never touch the v tiles.
  const unsigned short* ab = attnB + (size_t)bh * 9984;
#pragma unroll
  for (int i = 0; i < 5; i++) {
    int id = i * 256 + tid;
    int ids = id < 1248 ? id : 1247;
    gload16(ab + (size_t)ids * 8, &lds[(i * 4 + wid) * 512]);
  }

  // stage v chunk [128 n][96 e] -> [row][13 chunks] (13*16B = 208B row, 2-way banks)
  const unsigned short* vb = vT + (size_t)bh * 4096 * 96 + (size_t)n0 * 96;
#pragma unroll
  for (int i = 0; i < 7; i++) {
    int ig = wid + i * 4;                   // 0..27
    if (ig < 26) {
      int id = ig * 64 + lane;              // slot = row*13 + chunk
      int row = id / 13;
      int ch = id - row * 13;
      if (ch > 11) ch = 11;                 // pad slot: load harmless dup
      gload16(vb + (size_t)row * 96 + ch * 8, &lds[10240 + ig * 512]);
    }
  }
  __syncthreads();

  f32x4 acc[3][4];
  f32x4 z = {0.f, 0.f, 0.f, 0.f};
#pragma unroll
  for (int i = 0; i < 3; i++)
#pragma unroll
    for (int j = 0; j < 4; j++) acc[i][j] = z;
#pragma unroll
  for (int et = 0; et < 3; et++) {
    bf16x8 af[3], bfr[4];
#pragma unroll
    for (int mi = 0; mi < 3; mi++)
      af[mi] = *(const bf16x8*)&lds[(wm * 48 + mi * 16 + l16) * 104 + (et * 4 + quad) * 8];
#pragma unroll
    for (int ni = 0; ni < 4; ni++)
      bfr[ni] = *(const bf16x8*)&lds[10240 + (wn * 64 + ni * 16 + l16) * 104 + (et * 4 + quad) * 8];
#pragma unroll
    for (int mi = 0; mi < 3; mi++)
#pragma unroll
      for (int ni = 0; ni < 4; ni++)
        acc[mi][ni] = __builtin_amdgcn_mfma_f32_16x16x32_bf16(af[mi], bfr[ni], acc[mi][ni], 0, 0, 0);
  }
  __syncthreads();

  // bounce [128 n][104] then coalesced U writes
#pragma unroll
  for (int mi = 0; mi < 3; mi++)
#pragma unroll
    for (int ni = 0; ni < 4; ni++)
#pragma unroll
      for (int r = 0; r < 4; r++) {
        int d = wm * 48 + mi * 16 + quad * 4 + r;
        int n = wn * 64 + ni * 16 + l16;
        lds[n * 104 + d] = f2b(acc[mi][ni][r]);
      }
  __syncthreads();
#pragma unroll
  for (int it = 0; it < 6; it++) {
    int id = tid + it * 256;                // 128 n x 12 chunks
    int nr = id / 12, ch = id - nr * 12;
    *(uint4*)&U[((size_t)(b * 4096 + n0 + nr)) * 768 + h * 96 + ch * 8] =
        *(const uint4*)&lds[nr * 104 + ch * 8];
  }
}

// ---------------- GEMM3: y = U @ Wproj + bproj ----------------
__global__ __launch_bounds__(256, 2) void gemm_out(
    const unsigned short* __restrict__ A, const unsigned short* __restrict__ Bt,
    const float* __restrict__ bias, float* __restrict__ out) {
  __shared__ __align__(16) unsigned short lds[16384];
  int bj = blockIdx.x;                      // 0..5
  int bm = blockIdx.y;                      // 0..255
  int m0 = bm * 128, j0 = bj * 128;
  int tid = threadIdx.x;
  int wid = tid >> 6, lane = tid & 63;
  int wm = wid >> 1, wn = wid & 1;
  int quad = lane >> 4, l16 = lane & 15;
  int srow = lane >> 3, sch = lane & 7;
  int cmem = sch ^ srow;

  f32x4 acc[4][4];
  f32x4 z = {0.f, 0.f, 0.f, 0.f};
#pragma unroll
  for (int i = 0; i < 4; i++)
#pragma unroll
    for (int j = 0; j < 4; j++) acc[i][j] = z;

  const unsigned short* Ab = A + (size_t)m0 * 768;
  const unsigned short* Bb = Bt + (size_t)j0 * 768;

  for (int k0 = 0; k0 < 768; k0 += 64) {
#pragma unroll
    for (int i = 0; i < 4; i++) {
      int ig = wid * 4 + i;
      int row = ig * 8 + srow;
      gload16(Ab + (size_t)row * 768 + k0 + cmem * 8, &lds[ig * 512]);
      gload16(Bb + (size_t)row * 768 + k0 + cmem * 8, &lds[8192 + ig * 512]);
    }
    __syncthreads();
#pragma unroll
    for (int kk = 0; kk < 2; kk++) {
      int cs = ((kk * 4 + quad) ^ (l16 & 7)) * 8;
      bf16x8 af[4], bfr[4];
#pragma unroll
      for (int mi = 0; mi < 4; mi++)
        af[mi] = *(const bf16x8*)&lds[(wm * 64 + mi * 16 + l16) * 64 + cs];
#pragma unroll
      for (int ni = 0; ni < 4; ni++)
        bfr[ni] = *(const bf16x8*)&lds[8192 + (wn * 64 + ni * 16 + l16) * 64 + cs];
#pragma unroll
      for (int mi = 0; mi < 4; mi++)
#pragma unroll
        for (int ni = 0; ni < 4; ni++)
          acc[mi][ni] = __builtin_amdgcn_mfma_f32_16x16x32_bf16(af[mi], bfr[ni], acc[mi][ni], 0, 0, 0);
    }
    __syncthreads();
  }
#pragma unroll
  for (int ni = 0; ni < 4; ni++) {
    int ccol = j0 + wn * 64 + ni * 16 + l16;
    float bv = bias[ccol];
#pragma unroll
    for (int mi = 0; mi < 4; mi++)
#pragma unroll
      for (int r = 0; r < 4; r++)
        out[(size_t)(m0 + wm * 64 + mi * 16 + quad * 4 + r) * 768 + ccol] = acc[mi][ni][r] + bv;
  }
}

// ---------------- host ----------------
extern "C" void kernel_launch(void* const* d_in, const int* in_sizes, int n_in,
                              void* d_out, int out_size, void* d_ws, size_t ws_size,
                              hipStream_t stream) {
  const float* x = (const float*)d_in[0];
  const float* Wqkv = (const float*)d_in[1];
  const float* temp = (const float*)d_in[2];
  const float* Wproj = (const float*)d_in[3];
  const float* bproj = (const float*)d_in[4];
  float* out = (float*)d_out;
  char* ws = (char*)d_ws;

  unsigned short* xb     = (unsigned short*)(ws);                 // 50331648 B
  unsigned short* WqkvT  = (unsigned short*)(ws + 50331648);      // 3538944
  unsigned short* WprojT = (unsigned short*)(ws + 53870592);      // 1179648
  unsigned short* qkT    = (unsigned short*)(ws + 55050240);      // 100663296
  unsigned short* vT     = (unsigned short*)(ws + 155713536);     // 50331648
  unsigned short* U      = (unsigned short*)(ws + 206045184);     // 50331648
  float* S               = (float*)(ws + 256376832);              // 2359296
  float* normsq          = (float*)(ws + 258736128);              // 49152 (contiguous after S)
  // attnB aliases qkT (dead after attn_s): [64][96][104] bf16 = 1277952 B
  unsigned short* attnB  = qkT;

  cvt_bf16<<<dim3(4096), dim3(256), 0, stream>>>(x, xb, 25165824 / 4, S, 150528);
  cvt_transpose<<<dim3(72, 24), dim3(256), 0, stream>>>(Wqkv, WqkvT, 768, 2304);
  cvt_transpose<<<dim3(24, 24), dim3(256), 0, stream>>>(Wproj, WprojT, 768, 768);
  gemm_qkv<<<dim3(18, 256), dim3(256), 0, stream>>>(xb, WqkvT, qkT, vT, normsq);
  attn_s<<<dim3(512), dim3(256), 0, stream>>>(qkT, S);
  softmax96<<<dim3(64), dim3(128), 0, stream>>>(S, normsq, temp, attnB);
  attn_v<<<dim3(2048), dim3(256), 0, stream>>>(attnB, vT, U);
  gemm_out<<<dim3(6, 256), dim3(256), 0, stream>>>(U, WprojT, bproj, out);
}

// Round 2
// 442.569 us; speedup vs baseline: 1.0102x; 1.0102x over previous
//
#include <hip/hip_runtime.h>
#include <stdint.h>

// B=8, N=4096, C=768, H=8, hd=96. bf16 MFMA path.
// LDS tiles are row-major [rows][8 chunks of 8 elem] with XOR chunk swizzle:
// LDS slot (row, c) holds global chunk c ^ (row&7)  -> conflict-free ds_read_b128
// while global_load_lds staging stays contiguous (lanes permute within a 128B row).
// gemm_qkv: 256x256 tile, BK=64, 8 waves, 8-phase counted-vmcnt pipeline (T3+T4),
// setprio around MFMA clusters (T5), bijective XCD swizzle (T1).

typedef __attribute__((ext_vector_type(8))) __bf16 bf16x8;
typedef __attribute__((ext_vector_type(4))) float f32x4;

__device__ __forceinline__ unsigned short f2b(float f) {
  uint32_t u = __float_as_uint(f);
  u += 0x7FFF + ((u >> 16) & 1);
  return (unsigned short)(u >> 16);
}

__device__ __forceinline__ void gload16(const void* g, void* l) {
  __builtin_amdgcn_global_load_lds(
      (__attribute__((address_space(1))) void*)(uintptr_t)g,
      (__attribute__((address_space(3))) void*)(uintptr_t)l, 16, 0, 0);
}

// ---------------- conversions + zero S/normsq ----------------
__global__ void cvt_bf16(const float* __restrict__ in, unsigned short* __restrict__ out, int n4,
                         float* __restrict__ Z, int nz4) {
  int gid = blockIdx.x * blockDim.x + threadIdx.x;
  if (gid < nz4) reinterpret_cast<float4*>(Z)[gid] = make_float4(0.f, 0.f, 0.f, 0.f);
  int stride = gridDim.x * blockDim.x;
  for (int i = gid; i < n4; i += stride) {
    float4 v = reinterpret_cast<const float4*>(in)[i];
    ushort4 o;
    o.x = f2b(v.x); o.y = f2b(v.y); o.z = f2b(v.z); o.w = f2b(v.w);
    reinterpret_cast<ushort4*>(out)[i] = o;
  }
}

__global__ void cvt_transpose(const float* __restrict__ in, unsigned short* __restrict__ out,
                              int K, int NC) {
  __shared__ float tile[32][33];
  int bx = blockIdx.x, by = blockIdx.y;
  int tx = threadIdx.x & 31, ty = threadIdx.x >> 5;
  for (int r = ty; r < 32; r += 8)
    tile[r][tx] = in[(size_t)(by * 32 + r) * NC + bx * 32 + tx];
  __syncthreads();
  for (int r = ty; r < 32; r += 8)
    out[(size_t)(bx * 32 + r) * K + by * 32 + tx] = f2b(tile[tx][r]);
}

// ---------------- GEMM1: qkv = x @ Wqkv, 256^2 8-phase pipeline ----------------
// qkT: [2][64 bh][96 d][4096 n]; vT: [64 bh][4096 n][96 e]; normsq: [2][64][96]

#define BARX() asm volatile("s_barrier" ::: "memory")
#define WAITV(N) asm volatile("s_waitcnt vmcnt(" #N ")" ::: "memory")
#define SCHED() __builtin_amdgcn_sched_barrier(0)

// stage one half-tile (128 rows x 64 k-cols) into LDS buffer p (isB selects B region)
#define STAGE(gbase, p, isB, h, t) do {                                             \
  unsigned short* _lb = &lds[(p)*32768 + (isB)*16384 + (h)*8192 + wid*1024];        \
  const unsigned short* _gb = (gbase) + (size_t)((h)*128 + wid*16)*768 + (t)*64 + lanegoff; \
  gload16(_gb, _lb);                                                                \
  gload16(_gb + 8*768, _lb + 512);                                                  \
} while (0)

#define LOAD_AF(p, mh) do {                                                         \
  const unsigned short* _ab = &lds[(p)*32768 + (mh)*8192];                          \
  _Pragma("unroll") for (int _mi = 0; _mi < 4; _mi++)                               \
    _Pragma("unroll") for (int _kk = 0; _kk < 2; _kk++)                             \
      af[_mi][_kk] = *(const bf16x8*)&_ab[(wm*64 + _mi*16 + l16)*64 + ((_kk*4+quad)^(l16&7))*8]; \
} while (0)

#define LOAD_BF(dst, p, nh) do {                                                    \
  const unsigned short* _bb = &lds[(p)*32768 + 16384 + (nh)*8192];                  \
  _Pragma("unroll") for (int _ni = 0; _ni < 2; _ni++)                               \
    _Pragma("unroll") for (int _kk = 0; _kk < 2; _kk++)                             \
      dst[_ni][_kk] = *(const bf16x8*)&_bb[(wn*32 + _ni*16 + l16)*64 + ((_kk*4+quad)^(l16&7))*8]; \
} while (0)

#define MFMA_PH(mh, nh, bfx) do {                                                   \
  __builtin_amdgcn_s_setprio(1);                                                    \
  _Pragma("unroll") for (int _m = 0; _m < 4; _m++)                                  \
    _Pragma("unroll") for (int _n = 0; _n < 2; _n++)                                \
      _Pragma("unroll") for (int _k = 0; _k < 2; _k++)                              \
        acc[(mh)*4+_m][(nh)*2+_n] = __builtin_amdgcn_mfma_f32_16x16x32_bf16(        \
            af[_m][_k], bfx[_n][_k], acc[(mh)*4+_m][(nh)*2+_n], 0, 0, 0);           \
  __builtin_amdgcn_s_setprio(0);                                                    \
} while (0)

__global__ __launch_bounds__(512, 2) void gemm_qkv(
    const unsigned short* __restrict__ A, const unsigned short* __restrict__ Bt,
    unsigned short* __restrict__ qkT, unsigned short* __restrict__ vT,
    float* __restrict__ normsq) {
  __shared__ __align__(16) unsigned short lds[65536];  // 128 KiB: 2 buf x (A 256x64 + B 256x64)
  // bijective XCD swizzle over 1152 blocks (144 per XCD)
  int lin = blockIdx.y * 9 + blockIdx.x;
  int swz = (lin & 7) * 144 + (lin >> 3);
  int bm = swz / 9;
  int bj = swz - bm * 9;                      // 0..8 (256-wide col tiles)
  int m0 = bm * 256, j0 = bj * 256;
  int tid = threadIdx.x;
  int wid = tid >> 6, lane = tid & 63;
  int wm = wid >> 2, wn = wid & 3;            // 2 x 4 wave grid
  int quad = lane >> 4, l16 = lane & 15;
  int srow = lane >> 3, sch = lane & 7;
  int cmem = sch ^ srow;
  int lanegoff = srow * 768 + cmem * 8;

  f32x4 acc[8][4];
  f32x4 z = {0.f, 0.f, 0.f, 0.f};
#pragma unroll
  for (int i = 0; i < 8; i++)
#pragma unroll
    for (int j = 0; j < 4; j++) acc[i][j] = z;

  bf16x8 af[4][2], bf0[2][2], bf1[2][2];

  const unsigned short* Ab2 = A + (size_t)m0 * 768;
  const unsigned short* Bb2 = Bt + (size_t)j0 * 768;

  // prologue: tiles 0 and 1, half-tile order A0,B0,B1,A1 per tile (16 loads/wave)
  STAGE(Ab2, 0, 0, 0, 0); STAGE(Bb2, 0, 1, 0, 0); STAGE(Bb2, 0, 1, 1, 0); STAGE(Ab2, 0, 0, 1, 0);
  STAGE(Ab2, 1, 0, 0, 1); STAGE(Bb2, 1, 1, 0, 1); STAGE(Bb2, 1, 1, 1, 1); STAGE(Ab2, 1, 0, 1, 1);
  WAITV(12);   // A0(0),B0(0) landed (6 half-tiles in flight)
  BARX();

  // steady tiles 0..9 (stages for t+1 / t+2 alive; every wait = vmcnt(10), target issued 6-7 phases prior)
  for (int t = 0; t < 10; t++) {
    int p = t & 1;
    // Ph1 (mh0, nh0)
    LOAD_AF(p, 0); LOAD_BF(bf0, p, 0);
    if (t >= 1) STAGE(Ab2, p ^ 1, 0, 1, t + 1);   // A1(t+1) -> other buffer
    BARX(); SCHED();
    MFMA_PH(0, 0, bf0);
    SCHED(); WAITV(10); BARX();
    // Ph2 (mh0, nh1)
    LOAD_BF(bf1, p, 1);
    STAGE(Ab2, p, 0, 0, t + 2);                   // A0(t+2) -> same buffer (A0 reads done)
    BARX(); SCHED();
    MFMA_PH(0, 1, bf1);
    SCHED(); WAITV(10); BARX();
    // Ph3 (mh1, nh1)
    LOAD_AF(p, 1);
    STAGE(Bb2, p, 1, 0, t + 2);                   // B0(t+2)
    BARX(); SCHED();
    MFMA_PH(1, 1, bf1);
    SCHED(); BARX();
    // Ph4 (mh1, nh0)
    STAGE(Bb2, p, 1, 1, t + 2);                   // B1(t+2)
    BARX(); SCHED();
    MFMA_PH(1, 0, bf0);
    SCHED(); WAITV(10); BARX();
  }
  // tail t = 10 (p=0): only A1(11) left to stage
  LOAD_AF(0, 0); LOAD_BF(bf0, 0, 0);
  STAGE(Ab2, 1, 0, 1, 11);
  BARX(); SCHED(); MFMA_PH(0, 0, bf0); SCHED(); WAITV(10); BARX();
  LOAD_BF(bf1, 0, 1);
  BARX(); SCHED(); MFMA_PH(0, 1, bf1); SCHED(); WAITV(8); BARX();
  LOAD_AF(0, 1);
  BARX(); SCHED(); MFMA_PH(1, 1, bf1); SCHED(); BARX();
  BARX(); SCHED(); MFMA_PH(1, 0, bf0); SCHED(); WAITV(4); BARX();
  // tail t = 11 (p=1): no stages, drain
  LOAD_AF(1, 0); LOAD_BF(bf0, 1, 0);
  BARX(); SCHED(); MFMA_PH(0, 0, bf0); SCHED(); WAITV(2); BARX();
  LOAD_BF(bf1, 1, 1);
  BARX(); SCHED(); MFMA_PH(0, 1, bf1); SCHED(); WAITV(0); BARX();
  LOAD_AF(1, 1);
  BARX(); SCHED(); MFMA_PH(1, 1, bf1); SCHED(); BARX();
  BARX(); SCHED(); MFMA_PH(1, 0, bf0); SCHED(); BARX();

  // ---- epilogue ----
  // acc[mi][ni] covers row = (mi>>2)*128 + wm*64 + (mi&3)*16 + quad*4+r,
  //                  col = (ni>>1)*128 + wn*32 + (ni&1)*16 + l16   (within 256x256 tile)
  int s = bj / 3;                  // 0=q,1=k,2=v (BN=256: tiles 0-2 q, 3-5 k, 6-8 v)
  int b = m0 >> 12;
  int n0 = m0 & 4095;

  if (s < 2) {
    // fused norm^2 (fp32, pre-rounding)
#pragma unroll
    for (int ni = 0; ni < 4; ni++) {
      float ss = 0.f;
#pragma unroll
      for (int mi = 0; mi < 8; mi++)
#pragma unroll
        for (int r = 0; r < 4; r++) ss += acc[mi][ni][r] * acc[mi][ni][r];
      ss += __shfl_down(ss, 32, 64);
      ss += __shfl_down(ss, 16, 64);
      if (lane < 16) {
        int cc = (ni >> 1) * 128 + wn * 32 + (ni & 1) * 16 + l16;
        int local = j0 + cc - s * 768;
        int hh = local / 96, d = local - hh * 96;
        atomicAdd(&normsq[s * 6144 + (b * 8 + hh) * 96 + d], ss);
      }
    }
    // transpose-bounce in two 128-col halves: [128 j][256 n] stride 264
#pragma unroll
    for (int jh = 0; jh < 2; jh++) {
      __syncthreads();
#pragma unroll
      for (int nl = 0; nl < 2; nl++) {
        int ni = jh * 2 + nl;
        int jc = wn * 32 + nl * 16 + l16;
#pragma unroll
        for (int mi = 0; mi < 8; mi++) {
          int mrow = (mi >> 2) * 128 + wm * 64 + (mi & 3) * 16 + quad * 4;
#pragma unroll
          for (int r = 0; r < 4; r++) lds[jc * 264 + mrow + r] = f2b(acc[mi][ni][r]);
        }
      }
      __syncthreads();
#pragma unroll
      for (int it = 0; it < 8; it++) {
        int id = it * 512 + tid;             // 128 j x 32 n-chunks
        int jr = id >> 5, mc = id & 31;
        int j = j0 + jh * 128 + jr;
        int local = j - s * 768;
        int hh = local / 96, d = local - hh * 96;
        size_t off = ((size_t)(s * 64 + b * 8 + hh) * 96 + d) * 4096 + n0 + mc * 8;
        *(uint4*)&qkT[off] = *(const uint4*)&lds[jr * 264 + mc * 8];
      }
    }
  } else {
    // v: direct-orientation bounce in two 128-row halves: [128 n][256 j] stride 264
    int j0v = j0 - 1536;
#pragma unroll
    for (int mh = 0; mh < 2; mh++) {
      __syncthreads();
#pragma unroll
      for (int ml = 0; ml < 4; ml++) {
        int mi = mh * 4 + ml;
        int mloc = wm * 64 + ml * 16 + quad * 4;
#pragma unroll
        for (int ni = 0; ni < 4; ni++) {
          int jc = (ni >> 1) * 128 + wn * 32 + (ni & 1) * 16 + l16;
#pragma unroll
          for (int r = 0; r < 4; r++) lds[(mloc + r) * 264 + jc] = f2b(acc[mi][ni][r]);
        }
      }
      __syncthreads();
#pragma unroll
      for (int it = 0; it < 8; it++) {
        int id = it * 512 + tid;             // 128 n x 32 j-chunks
        int mr = id >> 5, ch = id & 31;
        int cp = j0v + ch * 8;
        int hh = cp / 96, e = cp - hh * 96;
        size_t off = ((size_t)(b * 8 + hh) * 4096 + (n0 + mh * 128 + mr)) * 96 + e;
        *(uint4*)&vT[off] = *(const uint4*)&lds[mr * 264 + ch * 8];
      }
    }
  }
}

// ---------------- split-K S = q @ k^T ----------------
__global__ __launch_bounds__(256, 2) void attn_s(const unsigned short* __restrict__ qkT,
                                                 float* __restrict__ S) {
  __shared__ __align__(16) unsigned short lds[12288];  // qs[96][64]@0, ks@6144 (swizzled)
  int blk = blockIdx.x;
  int bh = blk >> 3, ks = blk & 7;
  const unsigned short* qb = qkT + (size_t)bh * 96 * 4096;
  const unsigned short* kb = qkT + (size_t)(64 + bh) * 96 * 4096;
  int tid = threadIdx.x, wid = tid >> 6, lane = tid & 63;
  int wm = wid >> 1, wn = wid & 1, quad = lane >> 4, l16 = lane & 15;
  int srow = lane >> 3, sch = lane & 7;
  int cmem = sch ^ srow;
  f32x4 acc[3][3];
  f32x4 z = {0.f, 0.f, 0.f, 0.f};
#pragma unroll
  for (int i = 0; i < 3; i++)
#pragma unroll
    for (int j = 0; j < 3; j++) acc[i][j] = z;

  for (int k0 = ks * 512; k0 < ks * 512 + 512; k0 += 64) {
#pragma unroll
    for (int i = 0; i < 3; i++) {
      int ig = wid * 3 + i;                  // 0..11, 8 rows each
      int row = ig * 8 + srow;
      gload16(qb + (size_t)row * 4096 + k0 + cmem * 8, &lds[ig * 512]);
      gload16(kb + (size_t)row * 4096 + k0 + cmem * 8, &lds[6144 + ig * 512]);
    }
    __syncthreads();
#pragma unroll
    for (int kk = 0; kk < 2; kk++) {
      int cs = ((kk * 4 + quad) ^ (l16 & 7)) * 8;
      bf16x8 af[3], bfr[3];
#pragma unroll
      for (int mi = 0; mi < 3; mi++)
        af[mi] = *(const bf16x8*)&lds[(wm * 48 + mi * 16 + l16) * 64 + cs];
#pragma unroll
      for (int ni = 0; ni < 3; ni++)
        bfr[ni] = *(const bf16x8*)&lds[6144 + (wn * 48 + ni * 16 + l16) * 64 + cs];
#pragma unroll
      for (int mi = 0; mi < 3; mi++)
#pragma unroll
        for (int ni = 0; ni < 3; ni++)
          acc[mi][ni] = __builtin_amdgcn_mfma_f32_16x16x32_bf16(af[mi], bfr[ni], acc[mi][ni], 0, 0, 0);
    }
    __syncthreads();
  }
  float* Sb = S + (size_t)bh * 9216;
#pragma unroll
  for (int mi = 0; mi < 3; mi++)
#pragma unroll
    for (int ni = 0; ni < 3; ni++)
#pragma unroll
      for (int r = 0; r < 4; r++)
        atomicAdd(&Sb[(wm * 48 + mi * 16 + quad * 4 + r) * 96 + wn * 48 + ni * 16 + l16],
                  acc[mi][ni][r]);
}

// ---------------- softmax (once per bh): attnB = softmax(S*iq*ik) as bf16 [64][96][104] ----------------
__global__ __launch_bounds__(128) void softmax96(
    const float* __restrict__ S, const float* __restrict__ normsq,
    const float* __restrict__ temp, unsigned short* __restrict__ attnB) {
  __shared__ float ik[96];
  int bh = blockIdx.x;              // 0..63
  int h = bh & 7;
  int tid = threadIdx.x;
  if (tid < 96) ik[tid] = 1.0f / fmaxf(sqrtf(normsq[6144 + bh * 96 + tid]), 1e-12f);
  __syncthreads();
  if (tid < 96) {
    int d = tid;
    const float* Srow = S + (size_t)bh * 9216 + d * 96;
    float iq = (1.0f / fmaxf(sqrtf(normsq[bh * 96 + d]), 1e-12f)) * temp[h];
    float mx = -1e30f;
    for (int e = 0; e < 96; e++) mx = fmaxf(mx, Srow[e] * iq * ik[e]);
    float sum = 0.f;
    for (int e = 0; e < 96; e++) sum += __expf(Srow[e] * iq * ik[e] - mx);
    float inv = 1.0f / sum;
    unsigned short* row = attnB + (size_t)bh * 9984 + d * 104;
    for (int e = 0; e < 96; e++) row[e] = f2b(__expf(Srow[e] * iq * ik[e] - mx) * inv);
    for (int e = 96; e < 104; e++) row[e] = 0;  // pad chunk (never consumed by MFMA)
  }
}

// ---------------- out = attn @ v (attn pre-softmaxed) ----------------
__global__ __launch_bounds__(256, 2) void attn_v(
    const unsigned short* __restrict__ attnB, const unsigned short* __restrict__ vT,
    unsigned short* __restrict__ U) {
  // attn [96][104]@0 (padded dest region 10240), vs [128][13 chunks][8]@10240 (13312)
  __shared__ __align__(16) unsigned short lds[23552];
  int blk = blockIdx.x;
  int bh = blk >> 5, nc = blk & 31;
  int b = bh >> 3, h = bh & 7;
  int n0 = nc * 128;
  int tid = threadIdx.x, wid = tid >> 6, lane = tid & 63;
  int wm = wid >> 1, wn = wid & 1, quad = lane >> 4, l16 = lane & 15;

  // stage attn [96][104]: 1248 16B chunks, contiguous in global AND lds (stride 104 = 13 chunks).
  const unsigned short* ab = attnB + (size_t)bh * 9984;
#pragma unroll
  for (int i = 0; i < 5; i++) {
    int id = i * 256 + tid;
    int ids = id < 1248 ? id : 1247;
    gload16(ab + (size_t)ids * 8, &lds[(i * 4 + wid) * 512]);
  }

  // stage v chunk [128 n][96 e] -> [row][13 chunks] (13*16B = 208B row, 2-way banks)
  const unsigned short* vb = vT + (size_t)bh * 4096 * 96 + (size_t)n0 * 96;
#pragma unroll
  for (int i = 0; i < 7; i++) {
    int ig = wid + i * 4;                   // 0..27
    if (ig < 26) {
      int id = ig * 64 + lane;              // slot = row*13 + chunk
      int row = id / 13;
      int ch = id - row * 13;
      if (ch > 11) ch = 11;                 // pad slot: load harmless dup
      gload16(vb + (size_t)row * 96 + ch * 8, &lds[10240 + ig * 512]);
    }
  }
  __syncthreads();

  f32x4 acc[3][4];
  f32x4 z = {0.f, 0.f, 0.f, 0.f};
#pragma unroll
  for (int i = 0; i < 3; i++)
#pragma unroll
    for (int j = 0; j < 4; j++) acc[i][j] = z;
#pragma unroll
  for (int et = 0; et < 3; et++) {
    bf16x8 af[3], bfr[4];
#pragma unroll
    for (int mi = 0; mi < 3; mi++)
      af[mi] = *(const bf16x8*)&lds[(wm * 48 + mi * 16 + l16) * 104 + (et * 4 + quad) * 8];
#pragma unroll
    for (int ni = 0; ni < 4; ni++)
      bfr[ni] = *(const bf16x8*)&lds[10240 + (wn * 64 + ni * 16 + l16) * 104 + (et * 4 + quad) * 8];
#pragma unroll
    for (int mi = 0; mi < 3; mi++)
#pragma unroll
      for (int ni = 0; ni < 4; ni++)
        acc[mi][ni] = __builtin_amdgcn_mfma_f32_16x16x32_bf16(af[mi], bfr[ni], acc[mi][ni], 0, 0, 0);
  }
  __syncthreads();

  // bounce [128 n][104] then coalesced U writes
#pragma unroll
  for (int mi = 0; mi < 3; mi++)
#pragma unroll
    for (int ni = 0; ni < 4; ni++)
#pragma unroll
      for (int r = 0; r < 4; r++) {
        int d = wm * 48 + mi * 16 + quad * 4 + r;
        int n = wn * 64 + ni * 16 + l16;
        lds[n * 104 + d] = f2b(acc[mi][ni][r]);
      }
  __syncthreads();
#pragma unroll
  for (int it = 0; it < 6; it++) {
    int id = tid + it * 256;                // 128 n x 12 chunks
    int nr = id / 12, ch = id - nr * 12;
    *(uint4*)&U[((size_t)(b * 4096 + n0 + nr)) * 768 + h * 96 + ch * 8] =
        *(const uint4*)&lds[nr * 104 + ch * 8];
  }
}

// ---------------- GEMM3: y = U @ Wproj + bproj ----------------
__global__ __launch_bounds__(256, 2) void gemm_out(
    const unsigned short* __restrict__ A, const unsigned short* __restrict__ Bt,
    const float* __restrict__ bias, float* __restrict__ out) {
  __shared__ __align__(16) unsigned short lds[16384];
  int bj = blockIdx.x;                      // 0..5
  int bm = blockIdx.y;                      // 0..255
  int m0 = bm * 128, j0 = bj * 128;
  int tid = threadIdx.x;
  int wid = tid >> 6, lane = tid & 63;
  int wm = wid >> 1, wn = wid & 1;
  int quad = lane >> 4, l16 = lane & 15;
  int srow = lane >> 3, sch = lane & 7;
  int cmem = sch ^ srow;

  f32x4 acc[4][4];
  f32x4 z = {0.f, 0.f, 0.f, 0.f};
#pragma unroll
  for (int i = 0; i < 4; i++)
#pragma unroll
    for (int j = 0; j < 4; j++) acc[i][j] = z;

  const unsigned short* Ab = A + (size_t)m0 * 768;
  const unsigned short* Bb = Bt + (size_t)j0 * 768;

  for (int k0 = 0; k0 < 768; k0 += 64) {
#pragma unroll
    for (int i = 0; i < 4; i++) {
      int ig = wid * 4 + i;
      int row = ig * 8 + srow;
      gload16(Ab + (size_t)row * 768 + k0 + cmem * 8, &lds[ig * 512]);
      gload16(Bb + (size_t)row * 768 + k0 + cmem * 8, &lds[8192 + ig * 512]);
    }
    __syncthreads();
#pragma unroll
    for (int kk = 0; kk < 2; kk++) {
      int cs = ((kk * 4 + quad) ^ (l16 & 7)) * 8;
      bf16x8 af[4], bfr[4];
#pragma unroll
      for (int mi = 0; mi < 4; mi++)
        af[mi] = *(const bf16x8*)&lds[(wm * 64 + mi * 16 + l16) * 64 + cs];
#pragma unroll
      for (int ni = 0; ni < 4; ni++)
        bfr[ni] = *(const bf16x8*)&lds[8192 + (wn * 64 + ni * 16 + l16) * 64 + cs];
#pragma unroll
      for (int mi = 0; mi < 4; mi++)
#pragma unroll
        for (int ni = 0; ni < 4; ni++)
          acc[mi][ni] = __builtin_amdgcn_mfma_f32_16x16x32_bf16(af[mi], bfr[ni], acc[mi][ni], 0, 0, 0);
    }
    __syncthreads();
  }
#pragma unroll
  for (int ni = 0; ni < 4; ni++) {
    int ccol = j0 + wn * 64 + ni * 16 + l16;
    float bv = bias[ccol];
#pragma unroll
    for (int mi = 0; mi < 4; mi++)
#pragma unroll
      for (int r = 0; r < 4; r++)
        out[(size_t)(m0 + wm * 64 + mi * 16 + quad * 4 + r) * 768 + ccol] = acc[mi][ni][r] + bv;
  }
}

// ---------------- host ----------------
extern "C" void kernel_launch(void* const* d_in, const int* in_sizes, int n_in,
                              void* d_out, int out_size, void* d_ws, size_t ws_size,
                              hipStream_t stream) {
  const float* x = (const float*)d_in[0];
  const float* Wqkv = (const float*)d_in[1];
  const float* temp = (const float*)d_in[2];
  const float* Wproj = (const float*)d_in[3];
  const float* bproj = (const float*)d_in[4];
  float* out = (float*)d_out;
  char* ws = (char*)d_ws;

  unsigned short* xb     = (unsigned short*)(ws);                 // 50331648 B
  unsigned short* WqkvT  = (unsigned short*)(ws + 50331648);      // 3538944
  unsigned short* WprojT = (unsigned short*)(ws + 53870592);      // 1179648
  unsigned short* qkT    = (unsigned short*)(ws + 55050240);      // 100663296
  unsigned short* vT     = (unsigned short*)(ws + 155713536);     // 50331648
  unsigned short* U      = (unsigned short*)(ws + 206045184);     // 50331648
  float* S               = (float*)(ws + 256376832);              // 2359296
  float* normsq          = (float*)(ws + 258736128);              // 49152 (contiguous after S)
  // attnB aliases qkT (dead after attn_s): [64][96][104] bf16 = 1277952 B
  unsigned short* attnB  = qkT;

  cvt_bf16<<<dim3(4096), dim3(256), 0, stream>>>(x, xb, 25165824 / 4, S, 150528);
  cvt_transpose<<<dim3(72, 24), dim3(256), 0, stream>>>(Wqkv, WqkvT, 768, 2304);
  cvt_transpose<<<dim3(24, 24), dim3(256), 0, stream>>>(Wproj, WprojT, 768, 768);
  gemm_qkv<<<dim3(9, 128), dim3(512), 0, stream>>>(xb, WqkvT, qkT, vT, normsq);
  attn_s<<<dim3(512), dim3(256), 0, stream>>>(qkT, S);
  softmax96<<<dim3(64), dim3(128), 0, stream>>>(S, normsq, temp, attnB);
  attn_v<<<dim3(2048), dim3(256), 0, stream>>>(attnB, vT, U);
  gemm_out<<<dim3(6, 256), dim3(256), 0, stream>>>(U, WprojT, bproj, out);
}

// Round 3
// 434.421 us; speedup vs baseline: 1.0291x; 1.0188x over previous
//
#include <hip/hip_runtime.h>
#include <stdint.h>

// B=8, N=4096, C=768, H=8, hd=96. bf16 MFMA path.
// LDS tiles are row-major [rows][8 chunks of 8 elem] with XOR chunk swizzle:
// LDS slot (row, c) holds global chunk c ^ (row&7)  -> conflict-free ds_read_b128
// while global_load_lds staging stays contiguous (lanes permute within a 128B row).
// gemm_qkv: 256x256 tile, BK=64, 8 waves, 8-phase counted-vmcnt pipeline (T3+T4),
// one-phase fragment read-ahead (frag ds_reads issue >=1 phase before consuming MFMA,
// register-neutral: af reloaded post-MFMA, bf0 reloaded post-last-use), setprio (T5),
// bijective XCD swizzle (T1).

typedef __attribute__((ext_vector_type(8))) __bf16 bf16x8;
typedef __attribute__((ext_vector_type(4))) float f32x4;

__device__ __forceinline__ unsigned short f2b(float f) {
  uint32_t u = __float_as_uint(f);
  u += 0x7FFF + ((u >> 16) & 1);
  return (unsigned short)(u >> 16);
}

__device__ __forceinline__ void gload16(const void* g, void* l) {
  __builtin_amdgcn_global_load_lds(
      (__attribute__((address_space(1))) void*)(uintptr_t)g,
      (__attribute__((address_space(3))) void*)(uintptr_t)l, 16, 0, 0);
}

// ---------------- conversions + zero S/normsq ----------------
__global__ void cvt_bf16(const float* __restrict__ in, unsigned short* __restrict__ out, int n4,
                         float* __restrict__ Z, int nz4) {
  int gid = blockIdx.x * blockDim.x + threadIdx.x;
  if (gid < nz4) reinterpret_cast<float4*>(Z)[gid] = make_float4(0.f, 0.f, 0.f, 0.f);
  int stride = gridDim.x * blockDim.x;
  for (int i = gid; i < n4; i += stride) {
    float4 v = reinterpret_cast<const float4*>(in)[i];
    ushort4 o;
    o.x = f2b(v.x); o.y = f2b(v.y); o.z = f2b(v.z); o.w = f2b(v.w);
    reinterpret_cast<ushort4*>(out)[i] = o;
  }
}

__global__ void cvt_transpose(const float* __restrict__ in, unsigned short* __restrict__ out,
                              int K, int NC) {
  __shared__ float tile[32][33];
  int bx = blockIdx.x, by = blockIdx.y;
  int tx = threadIdx.x & 31, ty = threadIdx.x >> 5;
  for (int r = ty; r < 32; r += 8)
    tile[r][tx] = in[(size_t)(by * 32 + r) * NC + bx * 32 + tx];
  __syncthreads();
  for (int r = ty; r < 32; r += 8)
    out[(size_t)(bx * 32 + r) * K + by * 32 + tx] = f2b(tile[tx][r]);
}

// ---------------- GEMM1: qkv = x @ Wqkv, 256^2 8-phase pipeline ----------------
// qkT: [2][64 bh][96 d][4096 n]; vT: [64 bh][4096 n][96 e]; normsq: [2][64][96]

#define BARX() asm volatile("s_barrier" ::: "memory")
#define WAITV(N) asm volatile("s_waitcnt vmcnt(" #N ")" ::: "memory")
#define SCHED() __builtin_amdgcn_sched_barrier(0)

// stage one half-tile (128 rows x 64 k-cols) into LDS buffer p (isB selects B region)
#define STAGE(gbase, p, isB, h, t) do {                                             \
  unsigned short* _lb = &lds[(p)*32768 + (isB)*16384 + (h)*8192 + wid*1024];        \
  const unsigned short* _gb = (gbase) + (size_t)((h)*128 + wid*16)*768 + (t)*64 + lanegoff; \
  gload16(_gb, _lb);                                                                \
  gload16(_gb + 8*768, _lb + 512);                                                  \
} while (0)

#define LOAD_A(p, mh) do {                                                          \
  const unsigned short* _ab = &lds[(p)*32768 + (mh)*8192];                          \
  _Pragma("unroll") for (int _mi = 0; _mi < 4; _mi++)                               \
    _Pragma("unroll") for (int _kk = 0; _kk < 2; _kk++)                             \
      af[_mi][_kk] = *(const bf16x8*)&_ab[(wm*64 + _mi*16 + l16)*64 + ((_kk*4+quad)^(l16&7))*8]; \
} while (0)

#define LOAD_B(dst, p, nh) do {                                                     \
  const unsigned short* _bb = &lds[(p)*32768 + 16384 + (nh)*8192];                  \
  _Pragma("unroll") for (int _ni = 0; _ni < 2; _ni++)                               \
    _Pragma("unroll") for (int _kk = 0; _kk < 2; _kk++)                             \
      dst[_ni][_kk] = *(const bf16x8*)&_bb[(wn*32 + _ni*16 + l16)*64 + ((_kk*4+quad)^(l16&7))*8]; \
} while (0)

#define MFMA_PH(mh, nh, bfx) do {                                                   \
  __builtin_amdgcn_s_setprio(1);                                                    \
  _Pragma("unroll") for (int _m = 0; _m < 4; _m++)                                  \
    _Pragma("unroll") for (int _n = 0; _n < 2; _n++)                                \
      _Pragma("unroll") for (int _k = 0; _k < 2; _k++)                              \
        acc[(mh)*4+_m][(nh)*2+_n] = __builtin_amdgcn_mfma_f32_16x16x32_bf16(        \
            af[_m][_k], bfx[_n][_k], acc[(mh)*4+_m][(nh)*2+_n], 0, 0, 0);           \
  __builtin_amdgcn_s_setprio(0);                                                    \
} while (0)

__global__ __launch_bounds__(512, 2) void gemm_qkv(
    const unsigned short* __restrict__ A, const unsigned short* __restrict__ Bt,
    unsigned short* __restrict__ qkT, unsigned short* __restrict__ vT,
    float* __restrict__ normsq) {
  __shared__ __align__(16) unsigned short lds[65536];  // 128 KiB: 2 buf x (A 256x64 + B 256x64)
  // bijective XCD swizzle over 1152 blocks (144 per XCD)
  int lin = blockIdx.y * 9 + blockIdx.x;
  int swz = (lin & 7) * 144 + (lin >> 3);
  int bm = swz / 9;
  int bj = swz - bm * 9;                      // 0..8 (256-wide col tiles)
  int m0 = bm * 256, j0 = bj * 256;
  int tid = threadIdx.x;
  int wid = tid >> 6, lane = tid & 63;
  int wm = wid >> 2, wn = wid & 3;            // 2 x 4 wave grid
  int quad = lane >> 4, l16 = lane & 15;
  int srow = lane >> 3, sch = lane & 7;
  int cmem = sch ^ srow;
  int lanegoff = srow * 768 + cmem * 8;

  f32x4 acc[8][4];
  f32x4 z = {0.f, 0.f, 0.f, 0.f};
#pragma unroll
  for (int i = 0; i < 8; i++)
#pragma unroll
    for (int j = 0; j < 4; j++) acc[i][j] = z;

  bf16x8 af[4][2], bf0[2][2], bf1[2][2];

  const unsigned short* Ab2 = A + (size_t)m0 * 768;
  const unsigned short* Bb2 = Bt + (size_t)j0 * 768;

  // prologue: 7 half-tile stages, then preload af=A0(0), bf0=B0(0)
  STAGE(Ab2, 0, 0, 0, 0); STAGE(Bb2, 0, 1, 0, 0); STAGE(Bb2, 0, 1, 1, 0); STAGE(Ab2, 0, 0, 1, 0);
  STAGE(Ab2, 1, 0, 0, 1); STAGE(Bb2, 1, 1, 0, 1); STAGE(Bb2, 1, 1, 1, 1);
  WAITV(10);   // A0(0),B0(0) landed
  BARX();
  LOAD_A(0, 0);
  LOAD_B(bf0, 0, 0);
  WAITV(8);    // B1(0) landed (for P1(0)'s bf1 read)
  BARX();

  // steady tiles 0..9; every frag ds_read issues >=1 phase before its consuming MFMA
  for (int t = 0; t < 10; t++) {
    int p = t & 1;
    // P1: MFMA(0,0) uses af=A0(t) (loaded P4(t-1)-end), bf0=B0(t) (P4(t-1)-end)
    LOAD_B(bf1, p, 1);                            // bf1(t) -> used P2,P3
    STAGE(Ab2, p ^ 1, 0, 1, t + 1);               // A1(t+1)
    BARX(); SCHED();
    MFMA_PH(0, 0, bf0);
    SCHED(); WAITV(8); BARX();
    // P2: MFMA(0,1); then af <- A1(t) (used P3,P4)
    STAGE(Ab2, p, 0, 0, t + 2);                   // A0(t+2)
    BARX(); SCHED();
    MFMA_PH(0, 1, bf1);
    SCHED();
    LOAD_A(p, 1);
    BARX();
    // P3: MFMA(1,1)
    STAGE(Bb2, p, 1, 0, t + 2);                   // B0(t+2)
    BARX(); SCHED();
    MFMA_PH(1, 1, bf1);
    SCHED(); WAITV(8); BARX();
    // P4: MFMA(1,0); then af <- A0(t+1), bf0 <- B0(t+1) (both guaranteed since end-P3 wait)
    STAGE(Bb2, p, 1, 1, t + 2);                   // B1(t+2)
    BARX(); SCHED();
    MFMA_PH(1, 0, bf0);
    SCHED();
    LOAD_A(p ^ 1, 0);
    LOAD_B(bf0, p ^ 1, 0);
    WAITV(8); BARX();
  }
  // tail t=10 (p=0): only A1(11) left to stage
  LOAD_B(bf1, 0, 1);
  STAGE(Ab2, 1, 0, 1, 11);
  BARX(); SCHED(); MFMA_PH(0, 0, bf0); SCHED(); WAITV(8); BARX();
  BARX(); SCHED(); MFMA_PH(0, 1, bf1); SCHED(); LOAD_A(0, 1); BARX();
  BARX(); SCHED(); MFMA_PH(1, 1, bf1); SCHED(); WAITV(4); BARX();
  BARX(); SCHED(); MFMA_PH(1, 0, bf0); SCHED(); LOAD_A(1, 0); LOAD_B(bf0, 1, 0); WAITV(2); BARX();
  // tail t=11 (p=1): drain
  LOAD_B(bf1, 1, 1);
  BARX(); SCHED(); MFMA_PH(0, 0, bf0); SCHED(); WAITV(0); BARX();
  BARX(); SCHED(); MFMA_PH(0, 1, bf1); SCHED(); LOAD_A(1, 1); BARX();
  BARX(); SCHED(); MFMA_PH(1, 1, bf1); SCHED(); BARX();
  BARX(); SCHED(); MFMA_PH(1, 0, bf0); SCHED(); BARX();

  // ---- epilogue ----
  // acc[mi][ni] covers row = (mi>>2)*128 + wm*64 + (mi&3)*16 + quad*4+r,
  //                  col = (ni>>1)*128 + wn*32 + (ni&1)*16 + l16   (within 256x256 tile)
  int s = bj / 3;                  // 0=q,1=k,2=v (BN=256: tiles 0-2 q, 3-5 k, 6-8 v)
  int b = m0 >> 12;
  int n0 = m0 & 4095;

  if (s < 2) {
    // fused norm^2 (fp32, pre-rounding)
#pragma unroll
    for (int ni = 0; ni < 4; ni++) {
      float ss = 0.f;
#pragma unroll
      for (int mi = 0; mi < 8; mi++)
#pragma unroll
        for (int r = 0; r < 4; r++) ss += acc[mi][ni][r] * acc[mi][ni][r];
      ss += __shfl_down(ss, 32, 64);
      ss += __shfl_down(ss, 16, 64);
      if (lane < 16) {
        int cc = (ni >> 1) * 128 + wn * 32 + (ni & 1) * 16 + l16;
        int local = j0 + cc - s * 768;
        int hh = local / 96, d = local - hh * 96;
        atomicAdd(&normsq[s * 6144 + (b * 8 + hh) * 96 + d], ss);
      }
    }
    // transpose-bounce in two 128-col halves: [128 j][256 n] stride 264
#pragma unroll
    for (int jh = 0; jh < 2; jh++) {
      __syncthreads();
#pragma unroll
      for (int nl = 0; nl < 2; nl++) {
        int ni = jh * 2 + nl;
        int jc = wn * 32 + nl * 16 + l16;
#pragma unroll
        for (int mi = 0; mi < 8; mi++) {
          int mrow = (mi >> 2) * 128 + wm * 64 + (mi & 3) * 16 + quad * 4;
#pragma unroll
          for (int r = 0; r < 4; r++) lds[jc * 264 + mrow + r] = f2b(acc[mi][ni][r]);
        }
      }
      __syncthreads();
#pragma unroll
      for (int it = 0; it < 8; it++) {
        int id = it * 512 + tid;             // 128 j x 32 n-chunks
        int jr = id >> 5, mc = id & 31;
        int j = j0 + jh * 128 + jr;
        int local = j - s * 768;
        int hh = local / 96, d = local - hh * 96;
        size_t off = ((size_t)(s * 64 + b * 8 + hh) * 96 + d) * 4096 + n0 + mc * 8;
        *(uint4*)&qkT[off] = *(const uint4*)&lds[jr * 264 + mc * 8];
      }
    }
  } else {
    // v: direct-orientation bounce in two 128-row halves: [128 n][256 j] stride 264
    int j0v = j0 - 1536;
#pragma unroll
    for (int mh = 0; mh < 2; mh++) {
      __syncthreads();
#pragma unroll
      for (int ml = 0; ml < 4; ml++) {
        int mi = mh * 4 + ml;
        int mloc = wm * 64 + ml * 16 + quad * 4;
#pragma unroll
        for (int ni = 0; ni < 4; ni++) {
          int jc = (ni >> 1) * 128 + wn * 32 + (ni & 1) * 16 + l16;
#pragma unroll
          for (int r = 0; r < 4; r++) lds[(mloc + r) * 264 + jc] = f2b(acc[mi][ni][r]);
        }
      }
      __syncthreads();
#pragma unroll
      for (int it = 0; it < 8; it++) {
        int id = it * 512 + tid;             // 128 n x 32 j-chunks
        int mr = id >> 5, ch = id & 31;
        int cp = j0v + ch * 8;
        int hh = cp / 96, e = cp - hh * 96;
        size_t off = ((size_t)(b * 8 + hh) * 4096 + (n0 + mh * 128 + mr)) * 96 + e;
        *(uint4*)&vT[off] = *(const uint4*)&lds[mr * 264 + ch * 8];
      }
    }
  }
}

// ---------------- split-K S = q @ k^T ----------------
__global__ __launch_bounds__(256, 2) void attn_s(const unsigned short* __restrict__ qkT,
                                                 float* __restrict__ S) {
  __shared__ __align__(16) unsigned short lds[12288];  // qs[96][64]@0, ks@6144 (swizzled)
  int blk = blockIdx.x;
  int bh = blk >> 3, ks = blk & 7;
  const unsigned short* qb = qkT + (size_t)bh * 96 * 4096;
  const unsigned short* kb = qkT + (size_t)(64 + bh) * 96 * 4096;
  int tid = threadIdx.x, wid = tid >> 6, lane = tid & 63;
  int wm = wid >> 1, wn = wid & 1, quad = lane >> 4, l16 = lane & 15;
  int srow = lane >> 3, sch = lane & 7;
  int cmem = sch ^ srow;
  f32x4 acc[3][3];
  f32x4 z = {0.f, 0.f, 0.f, 0.f};
#pragma unroll
  for (int i = 0; i < 3; i++)
#pragma unroll
    for (int j = 0; j < 3; j++) acc[i][j] = z;

  for (int k0 = ks * 512; k0 < ks * 512 + 512; k0 += 64) {
#pragma unroll
    for (int i = 0; i < 3; i++) {
      int ig = wid * 3 + i;                  // 0..11, 8 rows each
      int row = ig * 8 + srow;
      gload16(qb + (size_t)row * 4096 + k0 + cmem * 8, &lds[ig * 512]);
      gload16(kb + (size_t)row * 4096 + k0 + cmem * 8, &lds[6144 + ig * 512]);
    }
    __syncthreads();
#pragma unroll
    for (int kk = 0; kk < 2; kk++) {
      int cs = ((kk * 4 + quad) ^ (l16 & 7)) * 8;
      bf16x8 af[3], bfr[3];
#pragma unroll
      for (int mi = 0; mi < 3; mi++)
        af[mi] = *(const bf16x8*)&lds[(wm * 48 + mi * 16 + l16) * 64 + cs];
#pragma unroll
      for (int ni = 0; ni < 3; ni++)
        bfr[ni] = *(const bf16x8*)&lds[6144 + (wn * 48 + ni * 16 + l16) * 64 + cs];
#pragma unroll
      for (int mi = 0; mi < 3; mi++)
#pragma unroll
        for (int ni = 0; ni < 3; ni++)
          acc[mi][ni] = __builtin_amdgcn_mfma_f32_16x16x32_bf16(af[mi], bfr[ni], acc[mi][ni], 0, 0, 0);
    }
    __syncthreads();
  }
  float* Sb = S + (size_t)bh * 9216;
#pragma unroll
  for (int mi = 0; mi < 3; mi++)
#pragma unroll
    for (int ni = 0; ni < 3; ni++)
#pragma unroll
      for (int r = 0; r < 4; r++)
        atomicAdd(&Sb[(wm * 48 + mi * 16 + quad * 4 + r) * 96 + wn * 48 + ni * 16 + l16],
                  acc[mi][ni][r]);
}

// ---------------- softmax (once per bh): attnB = softmax(S*iq*ik) as bf16 [64][96][104] ----------------
__global__ __launch_bounds__(128) void softmax96(
    const float* __restrict__ S, const float* __restrict__ normsq,
    const float* __restrict__ temp, unsigned short* __restrict__ attnB) {
  __shared__ float ik[96];
  int bh = blockIdx.x;              // 0..63
  int h = bh & 7;
  int tid = threadIdx.x;
  if (tid < 96) ik[tid] = 1.0f / fmaxf(sqrtf(normsq[6144 + bh * 96 + tid]), 1e-12f);
  __syncthreads();
  if (tid < 96) {
    int d = tid;
    const float* Srow = S + (size_t)bh * 9216 + d * 96;
    float iq = (1.0f / fmaxf(sqrtf(normsq[bh * 96 + d]), 1e-12f)) * temp[h];
    float mx = -1e30f;
    for (int e = 0; e < 96; e++) mx = fmaxf(mx, Srow[e] * iq * ik[e]);
    float sum = 0.f;
    for (int e = 0; e < 96; e++) sum += __expf(Srow[e] * iq * ik[e] - mx);
    float inv = 1.0f / sum;
    unsigned short* row = attnB + (size_t)bh * 9984 + d * 104;
    for (int e = 0; e < 96; e++) row[e] = f2b(__expf(Srow[e] * iq * ik[e] - mx) * inv);
    for (int e = 96; e < 104; e++) row[e] = 0;  // pad chunk (never consumed by MFMA)
  }
}

// ---------------- out = attn @ v (attn pre-softmaxed) ----------------
__global__ __launch_bounds__(256, 4) void attn_v(
    const unsigned short* __restrict__ attnB, const unsigned short* __restrict__ vT,
    unsigned short* __restrict__ U) {
  // attn [96][104]@0 (padded dest region 10240), vs [128][13 chunks][8]@10240 (13312)
  __shared__ __align__(16) unsigned short lds[23552];
  int blk = blockIdx.x;
  int bh = blk >> 5, nc = blk & 31;
  int b = bh >> 3, h = bh & 7;
  int n0 = nc * 128;
  int tid = threadIdx.x, wid = tid >> 6, lane = tid & 63;
  int wm = wid >> 1, wn = wid & 1, quad = lane >> 4, l16 = lane & 15;

  // stage attn [96][104]: 1248 16B chunks, contiguous in global AND lds (stride 104 = 13 chunks).
  const unsigned short* ab = attnB + (size_t)bh * 9984;
#pragma unroll
  for (int i = 0; i < 5; i++) {
    int id = i * 256 + tid;
    int ids = id < 1248 ? id : 1247;
    gload16(ab + (size_t)ids * 8, &lds[(i * 4 + wid) * 512]);
  }

  // stage v chunk [128 n][96 e] -> [row][13 chunks] (13*16B = 208B row, 2-way banks)
  const unsigned short* vb = vT + (size_t)bh * 4096 * 96 + (size_t)n0 * 96;
#pragma unroll
  for (int i = 0; i < 7; i++) {
    int ig = wid + i * 4;                   // 0..27
    if (ig < 26) {
      int id = ig * 64 + lane;              // slot = row*13 + chunk
      int row = id / 13;
      int ch = id - row * 13;
      if (ch > 11) ch = 11;                 // pad slot: load harmless dup
      gload16(vb + (size_t)row * 96 + ch * 8, &lds[10240 + ig * 512]);
    }
  }
  __syncthreads();

  f32x4 acc[3][4];
  f32x4 z = {0.f, 0.f, 0.f, 0.f};
#pragma unroll
  for (int i = 0; i < 3; i++)
#pragma unroll
    for (int j = 0; j < 4; j++) acc[i][j] = z;
#pragma unroll
  for (int et = 0; et < 3; et++) {
    bf16x8 af[3], bfr[4];
#pragma unroll
    for (int mi = 0; mi < 3; mi++)
      af[mi] = *(const bf16x8*)&lds[(wm * 48 + mi * 16 + l16) * 104 + (et * 4 + quad) * 8];
#pragma unroll
    for (int ni = 0; ni < 4; ni++)
      bfr[ni] = *(const bf16x8*)&lds[10240 + (wn * 64 + ni * 16 + l16) * 104 + (et * 4 + quad) * 8];
#pragma unroll
    for (int mi = 0; mi < 3; mi++)
#pragma unroll
      for (int ni = 0; ni < 4; ni++)
        acc[mi][ni] = __builtin_amdgcn_mfma_f32_16x16x32_bf16(af[mi], bfr[ni], acc[mi][ni], 0, 0, 0);
  }
  __syncthreads();

  // bounce [128 n][104] then coalesced U writes
#pragma unroll
  for (int mi = 0; mi < 3; mi++)
#pragma unroll
    for (int ni = 0; ni < 4; ni++)
#pragma unroll
      for (int r = 0; r < 4; r++) {
        int d = wm * 48 + mi * 16 + quad * 4 + r;
        int n = wn * 64 + ni * 16 + l16;
        lds[n * 104 + d] = f2b(acc[mi][ni][r]);
      }
  __syncthreads();
#pragma unroll
  for (int it = 0; it < 6; it++) {
    int id = tid + it * 256;                // 128 n x 12 chunks
    int nr = id / 12, ch = id - nr * 12;
    *(uint4*)&U[((size_t)(b * 4096 + n0 + nr)) * 768 + h * 96 + ch * 8] =
        *(const uint4*)&lds[nr * 104 + ch * 8];
  }
}

// ---------------- GEMM3: y = U @ Wproj + bproj ----------------
__global__ __launch_bounds__(256, 2) void gemm_out(
    const unsigned short* __restrict__ A, const unsigned short* __restrict__ Bt,
    const float* __restrict__ bias, float* __restrict__ out) {
  __shared__ __align__(16) unsigned short lds[16384];
  int bj = blockIdx.x;                      // 0..5
  int bm = blockIdx.y;                      // 0..255
  int m0 = bm * 128, j0 = bj * 128;
  int tid = threadIdx.x;
  int wid = tid >> 6, lane = tid & 63;
  int wm = wid >> 1, wn = wid & 1;
  int quad = lane >> 4, l16 = lane & 15;
  int srow = lane >> 3, sch = lane & 7;
  int cmem = sch ^ srow;

  f32x4 acc[4][4];
  f32x4 z = {0.f, 0.f, 0.f, 0.f};
#pragma unroll
  for (int i = 0; i < 4; i++)
#pragma unroll
    for (int j = 0; j < 4; j++) acc[i][j] = z;

  const unsigned short* Ab = A + (size_t)m0 * 768;
  const unsigned short* Bb = Bt + (size_t)j0 * 768;

  for (int k0 = 0; k0 < 768; k0 += 64) {
#pragma unroll
    for (int i = 0; i < 4; i++) {
      int ig = wid * 4 + i;
      int row = ig * 8 + srow;
      gload16(Ab + (size_t)row * 768 + k0 + cmem * 8, &lds[ig * 512]);
      gload16(Bb + (size_t)row * 768 + k0 + cmem * 8, &lds[8192 + ig * 512]);
    }
    __syncthreads();
#pragma unroll
    for (int kk = 0; kk < 2; kk++) {
      int cs = ((kk * 4 + quad) ^ (l16 & 7)) * 8;
      bf16x8 af[4], bfr[4];
#pragma unroll
      for (int mi = 0; mi < 4; mi++)
        af[mi] = *(const bf16x8*)&lds[(wm * 64 + mi * 16 + l16) * 64 + cs];
#pragma unroll
      for (int ni = 0; ni < 4; ni++)
        bfr[ni] = *(const bf16x8*)&lds[8192 + (wn * 64 + ni * 16 + l16) * 64 + cs];
#pragma unroll
      for (int mi = 0; mi < 4; mi++)
#pragma unroll
        for (int ni = 0; ni < 4; ni++)
          acc[mi][ni] = __builtin_amdgcn_mfma_f32_16x16x32_bf16(af[mi], bfr[ni], acc[mi][ni], 0, 0, 0);
    }
    __syncthreads();
  }
#pragma unroll
  for (int ni = 0; ni < 4; ni++) {
    int ccol = j0 + wn * 64 + ni * 16 + l16;
    float bv = bias[ccol];
#pragma unroll
    for (int mi = 0; mi < 4; mi++)
#pragma unroll
      for (int r = 0; r < 4; r++)
        out[(size_t)(m0 + wm * 64 + mi * 16 + quad * 4 + r) * 768 + ccol] = acc[mi][ni][r] + bv;
  }
}

// ---------------- host ----------------
extern "C" void kernel_launch(void* const* d_in, const int* in_sizes, int n_in,
                              void* d_out, int out_size, void* d_ws, size_t ws_size,
                              hipStream_t stream) {
  const float* x = (const float*)d_in[0];
  const float* Wqkv = (const float*)d_in[1];
  const float* temp = (const float*)d_in[2];
  const float* Wproj = (const float*)d_in[3];
  const float* bproj = (const float*)d_in[4];
  float* out = (float*)d_out;
  char* ws = (char*)d_ws;

  unsigned short* xb     = (unsigned short*)(ws);                 // 50331648 B
  unsigned short* WqkvT  = (unsigned short*)(ws + 50331648);      // 3538944
  unsigned short* WprojT = (unsigned short*)(ws + 53870592);      // 1179648
  unsigned short* qkT    = (unsigned short*)(ws + 55050240);      // 100663296
  unsigned short* vT     = (unsigned short*)(ws + 155713536);     // 50331648
  unsigned short* U      = (unsigned short*)(ws + 206045184);     // 50331648
  float* S               = (float*)(ws + 256376832);              // 2359296
  float* normsq          = (float*)(ws + 258736128);              // 49152 (contiguous after S)
  // attnB aliases qkT (dead after attn_s): [64][96][104] bf16 = 1277952 B
  unsigned short* attnB  = qkT;

  cvt_bf16<<<dim3(4096), dim3(256), 0, stream>>>(x, xb, 25165824 / 4, S, 150528);
  cvt_transpose<<<dim3(72, 24), dim3(256), 0, stream>>>(Wqkv, WqkvT, 768, 2304);
  cvt_transpose<<<dim3(24, 24), dim3(256), 0, stream>>>(Wproj, WprojT, 768, 768);
  gemm_qkv<<<dim3(9, 128), dim3(512), 0, stream>>>(xb, WqkvT, qkT, vT, normsq);
  attn_s<<<dim3(512), dim3(256), 0, stream>>>(qkT, S);
  softmax96<<<dim3(64), dim3(128), 0, stream>>>(S, normsq, temp, attnB);
  attn_v<<<dim3(2048), dim3(256), 0, stream>>>(attnB, vT, U);
  gemm_out<<<dim3(6, 256), dim3(256), 0, stream>>>(U, WprojT, bproj, out);
}

// Round 4
// 426.355 us; speedup vs baseline: 1.0486x; 1.0189x over previous
//
#include <hip/hip_runtime.h>
#include <stdint.h>

// B=8, N=4096, C=768, H=8, hd=96. bf16 MFMA path.
// LDS tiles are row-major [rows][8 chunks of 8 elem] with XOR chunk swizzle:
// LDS slot (row, c) holds global chunk c ^ (row&7)  -> conflict-free ds_read_b128
// while global_load_lds staging stays contiguous (lanes permute within a 128B row).
// gemm_qkv: 256x256 tile, BK=64, 8 waves, 8-phase counted-vmcnt pipeline (T3+T4),
// one-phase fragment read-ahead, setprio (T5), bijective XCD swizzle (T1).
// attn_s: atomic-free split-K -> S8 partials; softmax96 reduces 8 partials.

typedef __attribute__((ext_vector_type(8))) __bf16 bf16x8;
typedef __attribute__((ext_vector_type(4))) float f32x4;

__device__ __forceinline__ unsigned short f2b(float f) {
  uint32_t u = __float_as_uint(f);
  u += 0x7FFF + ((u >> 16) & 1);
  return (unsigned short)(u >> 16);
}

__device__ __forceinline__ void gload16(const void* g, void* l) {
  __builtin_amdgcn_global_load_lds(
      (__attribute__((address_space(1))) void*)(uintptr_t)g,
      (__attribute__((address_space(3))) void*)(uintptr_t)l, 16, 0, 0);
}

// ---------------- conversions + zero normsq ----------------
__global__ void cvt_bf16(const float* __restrict__ in, unsigned short* __restrict__ out, int n4,
                         float* __restrict__ Z, int nz4) {
  int gid = blockIdx.x * blockDim.x + threadIdx.x;
  if (gid < nz4) reinterpret_cast<float4*>(Z)[gid] = make_float4(0.f, 0.f, 0.f, 0.f);
  int stride = gridDim.x * blockDim.x;
  for (int i = gid; i < n4; i += stride) {
    float4 v = reinterpret_cast<const float4*>(in)[i];
    ushort4 o;
    o.x = f2b(v.x); o.y = f2b(v.y); o.z = f2b(v.z); o.w = f2b(v.w);
    reinterpret_cast<ushort4*>(out)[i] = o;
  }
}

__global__ void cvt_transpose(const float* __restrict__ in, unsigned short* __restrict__ out,
                              int K, int NC) {
  __shared__ float tile[32][33];
  int bx = blockIdx.x, by = blockIdx.y;
  int tx = threadIdx.x & 31, ty = threadIdx.x >> 5;
  for (int r = ty; r < 32; r += 8)
    tile[r][tx] = in[(size_t)(by * 32 + r) * NC + bx * 32 + tx];
  __syncthreads();
  for (int r = ty; r < 32; r += 8)
    out[(size_t)(bx * 32 + r) * K + by * 32 + tx] = f2b(tile[tx][r]);
}

// ---------------- GEMM1: qkv = x @ Wqkv, 256^2 8-phase pipeline ----------------
// qkT: [2][64 bh][96 d][4096 n]; vT: [64 bh][4096 n][96 e]; normsq: [2][64][96]

#define BARX() asm volatile("s_barrier" ::: "memory")
#define WAITV(N) asm volatile("s_waitcnt vmcnt(" #N ")" ::: "memory")
#define SCHED() __builtin_amdgcn_sched_barrier(0)

// stage one half-tile (128 rows x 64 k-cols) into LDS buffer p (isB selects B region)
#define STAGE(gbase, p, isB, h, t) do {                                             \
  unsigned short* _lb = &lds[(p)*32768 + (isB)*16384 + (h)*8192 + wid*1024];        \
  const unsigned short* _gb = (gbase) + (size_t)((h)*128 + wid*16)*768 + (t)*64 + lanegoff; \
  gload16(_gb, _lb);                                                                \
  gload16(_gb + 8*768, _lb + 512);                                                  \
} while (0)

#define LOAD_A(p, mh) do {                                                          \
  const unsigned short* _ab = &lds[(p)*32768 + (mh)*8192];                          \
  _Pragma("unroll") for (int _mi = 0; _mi < 4; _mi++)                               \
    _Pragma("unroll") for (int _kk = 0; _kk < 2; _kk++)                             \
      af[_mi][_kk] = *(const bf16x8*)&_ab[(wm*64 + _mi*16 + l16)*64 + ((_kk*4+quad)^(l16&7))*8]; \
} while (0)

#define LOAD_B(dst, p, nh) do {                                                     \
  const unsigned short* _bb = &lds[(p)*32768 + 16384 + (nh)*8192];                  \
  _Pragma("unroll") for (int _ni = 0; _ni < 2; _ni++)                               \
    _Pragma("unroll") for (int _kk = 0; _kk < 2; _kk++)                             \
      dst[_ni][_kk] = *(const bf16x8*)&_bb[(wn*32 + _ni*16 + l16)*64 + ((_kk*4+quad)^(l16&7))*8]; \
} while (0)

#define MFMA_PH(mh, nh, bfx) do {                                                   \
  __builtin_amdgcn_s_setprio(1);                                                    \
  _Pragma("unroll") for (int _m = 0; _m < 4; _m++)                                  \
    _Pragma("unroll") for (int _n = 0; _n < 2; _n++)                                \
      _Pragma("unroll") for (int _k = 0; _k < 2; _k++)                              \
        acc[(mh)*4+_m][(nh)*2+_n] = __builtin_amdgcn_mfma_f32_16x16x32_bf16(        \
            af[_m][_k], bfx[_n][_k], acc[(mh)*4+_m][(nh)*2+_n], 0, 0, 0);           \
  __builtin_amdgcn_s_setprio(0);                                                    \
} while (0)

__global__ __launch_bounds__(512, 2) void gemm_qkv(
    const unsigned short* __restrict__ A, const unsigned short* __restrict__ Bt,
    unsigned short* __restrict__ qkT, unsigned short* __restrict__ vT,
    float* __restrict__ normsq) {
  __shared__ __align__(16) unsigned short lds[65536];  // 128 KiB: 2 buf x (A 256x64 + B 256x64)
  // bijective XCD swizzle over 1152 blocks (144 per XCD)
  int lin = blockIdx.y * 9 + blockIdx.x;
  int swz = (lin & 7) * 144 + (lin >> 3);
  int bm = swz / 9;
  int bj = swz - bm * 9;                      // 0..8 (256-wide col tiles)
  int m0 = bm * 256, j0 = bj * 256;
  int tid = threadIdx.x;
  int wid = tid >> 6, lane = tid & 63;
  int wm = wid >> 2, wn = wid & 3;            // 2 x 4 wave grid
  int quad = lane >> 4, l16 = lane & 15;
  int srow = lane >> 3, sch = lane & 7;
  int cmem = sch ^ srow;
  int lanegoff = srow * 768 + cmem * 8;

  f32x4 acc[8][4];
  f32x4 z = {0.f, 0.f, 0.f, 0.f};
#pragma unroll
  for (int i = 0; i < 8; i++)
#pragma unroll
    for (int j = 0; j < 4; j++) acc[i][j] = z;

  bf16x8 af[4][2], bf0[2][2], bf1[2][2];

  const unsigned short* Ab2 = A + (size_t)m0 * 768;
  const unsigned short* Bb2 = Bt + (size_t)j0 * 768;

  // prologue: 7 half-tile stages, then preload af=A0(0), bf0=B0(0)
  STAGE(Ab2, 0, 0, 0, 0); STAGE(Bb2, 0, 1, 0, 0); STAGE(Bb2, 0, 1, 1, 0); STAGE(Ab2, 0, 0, 1, 0);
  STAGE(Ab2, 1, 0, 0, 1); STAGE(Bb2, 1, 1, 0, 1); STAGE(Bb2, 1, 1, 1, 1);
  WAITV(10);   // A0(0),B0(0) landed
  BARX();
  LOAD_A(0, 0);
  LOAD_B(bf0, 0, 0);
  WAITV(8);    // B1(0) landed (for P1(0)'s bf1 read)
  BARX();

  // steady tiles 0..9; every frag ds_read issues >=1 phase before its consuming MFMA
  for (int t = 0; t < 10; t++) {
    int p = t & 1;
    // P1: MFMA(0,0) uses af=A0(t) (loaded P4(t-1)-end), bf0=B0(t) (P4(t-1)-end)
    LOAD_B(bf1, p, 1);                            // bf1(t) -> used P2,P3
    STAGE(Ab2, p ^ 1, 0, 1, t + 1);               // A1(t+1)
    BARX(); SCHED();
    MFMA_PH(0, 0, bf0);
    SCHED(); WAITV(8); BARX();
    // P2: MFMA(0,1); then af <- A1(t) (used P3,P4)
    STAGE(Ab2, p, 0, 0, t + 2);                   // A0(t+2)
    BARX(); SCHED();
    MFMA_PH(0, 1, bf1);
    SCHED();
    LOAD_A(p, 1);
    BARX();
    // P3: MFMA(1,1)
    STAGE(Bb2, p, 1, 0, t + 2);                   // B0(t+2)
    BARX(); SCHED();
    MFMA_PH(1, 1, bf1);
    SCHED(); WAITV(8); BARX();
    // P4: MFMA(1,0); then af <- A0(t+1), bf0 <- B0(t+1) (both guaranteed since end-P3 wait)
    STAGE(Bb2, p, 1, 1, t + 2);                   // B1(t+2)
    BARX(); SCHED();
    MFMA_PH(1, 0, bf0);
    SCHED();
    LOAD_A(p ^ 1, 0);
    LOAD_B(bf0, p ^ 1, 0);
    WAITV(8); BARX();
  }
  // tail t=10 (p=0): only A1(11) left to stage
  LOAD_B(bf1, 0, 1);
  STAGE(Ab2, 1, 0, 1, 11);
  BARX(); SCHED(); MFMA_PH(0, 0, bf0); SCHED(); WAITV(8); BARX();
  BARX(); SCHED(); MFMA_PH(0, 1, bf1); SCHED(); LOAD_A(0, 1); BARX();
  BARX(); SCHED(); MFMA_PH(1, 1, bf1); SCHED(); WAITV(4); BARX();
  BARX(); SCHED(); MFMA_PH(1, 0, bf0); SCHED(); LOAD_A(1, 0); LOAD_B(bf0, 1, 0); WAITV(2); BARX();
  // tail t=11 (p=1): drain
  LOAD_B(bf1, 1, 1);
  BARX(); SCHED(); MFMA_PH(0, 0, bf0); SCHED(); WAITV(0); BARX();
  BARX(); SCHED(); MFMA_PH(0, 1, bf1); SCHED(); LOAD_A(1, 1); BARX();
  BARX(); SCHED(); MFMA_PH(1, 1, bf1); SCHED(); BARX();
  BARX(); SCHED(); MFMA_PH(1, 0, bf0); SCHED(); BARX();

  // ---- epilogue ----
  int s = bj / 3;                  // 0=q,1=k,2=v (BN=256: tiles 0-2 q, 3-5 k, 6-8 v)
  int b = m0 >> 12;
  int n0 = m0 & 4095;

  if (s < 2) {
    // fused norm^2 (fp32, pre-rounding)
#pragma unroll
    for (int ni = 0; ni < 4; ni++) {
      float ss = 0.f;
#pragma unroll
      for (int mi = 0; mi < 8; mi++)
#pragma unroll
        for (int r = 0; r < 4; r++) ss += acc[mi][ni][r] * acc[mi][ni][r];
      ss += __shfl_down(ss, 32, 64);
      ss += __shfl_down(ss, 16, 64);
      if (lane < 16) {
        int cc = (ni >> 1) * 128 + wn * 32 + (ni & 1) * 16 + l16;
        int local = j0 + cc - s * 768;
        int hh = local / 96, d = local - hh * 96;
        atomicAdd(&normsq[s * 6144 + (b * 8 + hh) * 96 + d], ss);
      }
    }
    // transpose-bounce in two 128-col halves: [128 j][256 n] stride 264
#pragma unroll
    for (int jh = 0; jh < 2; jh++) {
      __syncthreads();
#pragma unroll
      for (int nl = 0; nl < 2; nl++) {
        int ni = jh * 2 + nl;
        int jc = wn * 32 + nl * 16 + l16;
#pragma unroll
        for (int mi = 0; mi < 8; mi++) {
          int mrow = (mi >> 2) * 128 + wm * 64 + (mi & 3) * 16 + quad * 4;
#pragma unroll
          for (int r = 0; r < 4; r++) lds[jc * 264 + mrow + r] = f2b(acc[mi][ni][r]);
        }
      }
      __syncthreads();
#pragma unroll
      for (int it = 0; it < 8; it++) {
        int id = it * 512 + tid;             // 128 j x 32 n-chunks
        int jr = id >> 5, mc = id & 31;
        int j = j0 + jh * 128 + jr;
        int local = j - s * 768;
        int hh = local / 96, d = local - hh * 96;
        size_t off = ((size_t)(s * 64 + b * 8 + hh) * 96 + d) * 4096 + n0 + mc * 8;
        *(uint4*)&qkT[off] = *(const uint4*)&lds[jr * 264 + mc * 8];
      }
    }
  } else {
    // v: direct-orientation bounce in two 128-row halves: [128 n][256 j] stride 264
    int j0v = j0 - 1536;
#pragma unroll
    for (int mh = 0; mh < 2; mh++) {
      __syncthreads();
#pragma unroll
      for (int ml = 0; ml < 4; ml++) {
        int mi = mh * 4 + ml;
        int mloc = wm * 64 + ml * 16 + quad * 4;
#pragma unroll
        for (int ni = 0; ni < 4; ni++) {
          int jc = (ni >> 1) * 128 + wn * 32 + (ni & 1) * 16 + l16;
#pragma unroll
          for (int r = 0; r < 4; r++) lds[(mloc + r) * 264 + jc] = f2b(acc[mi][ni][r]);
        }
      }
      __syncthreads();
#pragma unroll
      for (int it = 0; it < 8; it++) {
        int id = it * 512 + tid;             // 128 n x 32 j-chunks
        int mr = id >> 5, ch = id & 31;
        int cp = j0v + ch * 8;
        int hh = cp / 96, e = cp - hh * 96;
        size_t off = ((size_t)(b * 8 + hh) * 4096 + (n0 + mh * 128 + mr)) * 96 + e;
        *(uint4*)&vT[off] = *(const uint4*)&lds[mr * 264 + ch * 8];
      }
    }
  }
}

// ---------------- split-K S partials: S8[ks][bh][96][96], plain stores ----------------
__global__ __launch_bounds__(256, 2) void attn_s(const unsigned short* __restrict__ qkT,
                                                 float* __restrict__ S8) {
  __shared__ __align__(16) unsigned short lds[12288];  // qs[96][64]@0, ks@6144 (swizzled)
  int blk = blockIdx.x;
  int bh = blk >> 3, ks = blk & 7;
  const unsigned short* qb = qkT + (size_t)bh * 96 * 4096;
  const unsigned short* kb = qkT + (size_t)(64 + bh) * 96 * 4096;
  int tid = threadIdx.x, wid = tid >> 6, lane = tid & 63;
  int wm = wid >> 1, wn = wid & 1, quad = lane >> 4, l16 = lane & 15;
  int srow = lane >> 3, sch = lane & 7;
  int cmem = sch ^ srow;
  f32x4 acc[3][3];
  f32x4 z = {0.f, 0.f, 0.f, 0.f};
#pragma unroll
  for (int i = 0; i < 3; i++)
#pragma unroll
    for (int j = 0; j < 3; j++) acc[i][j] = z;

  for (int k0 = ks * 512; k0 < ks * 512 + 512; k0 += 64) {
#pragma unroll
    for (int i = 0; i < 3; i++) {
      int ig = wid * 3 + i;                  // 0..11, 8 rows each
      int row = ig * 8 + srow;
      gload16(qb + (size_t)row * 4096 + k0 + cmem * 8, &lds[ig * 512]);
      gload16(kb + (size_t)row * 4096 + k0 + cmem * 8, &lds[6144 + ig * 512]);
    }
    __syncthreads();
#pragma unroll
    for (int kk = 0; kk < 2; kk++) {
      int cs = ((kk * 4 + quad) ^ (l16 & 7)) * 8;
      bf16x8 af[3], bfr[3];
#pragma unroll
      for (int mi = 0; mi < 3; mi++)
        af[mi] = *(const bf16x8*)&lds[(wm * 48 + mi * 16 + l16) * 64 + cs];
#pragma unroll
      for (int ni = 0; ni < 3; ni++)
        bfr[ni] = *(const bf16x8*)&lds[6144 + (wn * 48 + ni * 16 + l16) * 64 + cs];
#pragma unroll
      for (int mi = 0; mi < 3; mi++)
#pragma unroll
        for (int ni = 0; ni < 3; ni++)
          acc[mi][ni] = __builtin_amdgcn_mfma_f32_16x16x32_bf16(af[mi], bfr[ni], acc[mi][ni], 0, 0, 0);
    }
    __syncthreads();
  }
  // plain stores: [row d][col e]; per store instr: 4 quads x 16 l16 = 4 x 64B segments
  float* Sb = S8 + ((size_t)ks * 64 + bh) * 9216;
#pragma unroll
  for (int mi = 0; mi < 3; mi++)
#pragma unroll
    for (int ni = 0; ni < 3; ni++)
#pragma unroll
      for (int r = 0; r < 4; r++)
        Sb[(wm * 48 + mi * 16 + quad * 4 + r) * 96 + wn * 48 + ni * 16 + l16] = acc[mi][ni][r];
}

// ---------------- softmax: reduce 8 S-partials + softmax -> attnB [64][96][104] bf16 ----------------
__global__ __launch_bounds__(256) void softmax96(
    const float* __restrict__ S8, const float* __restrict__ normsq,
    const float* __restrict__ temp, unsigned short* __restrict__ attnB) {
  __shared__ float Sl[24][97];
  __shared__ float ik[96], iqv[24];
  int part = blockIdx.x;            // 0..3 (24 d-rows each)
  int bh = blockIdx.y;              // 0..63
  int h = bh & 7;
  int base = part * 24;
  int tid = threadIdx.x;
  if (tid < 96) {
    ik[tid] = 1.0f / fmaxf(sqrtf(normsq[6144 + bh * 96 + tid]), 1e-12f);
  } else if (tid >= 128 && tid < 152) {
    int d = base + tid - 128;
    iqv[tid - 128] = (1.0f / fmaxf(sqrtf(normsq[bh * 96 + d]), 1e-12f)) * temp[h];
  }
  // sum 8 partials for this 24x96 block (coalesced: e-major)
  const float* Sbase = S8 + (size_t)bh * 9216 + base * 96;
#pragma unroll
  for (int i = 0; i < 9; i++) {
    int idx = i * 256 + tid;        // 0..2303
    int r = idx / 96, e = idx - r * 96;
    float s = 0.f;
#pragma unroll
    for (int ksb = 0; ksb < 8; ksb++) s += Sbase[(size_t)ksb * 589824 + r * 96 + e];
    Sl[r][e] = s;
  }
  __syncthreads();
  // wave-per-row softmax (row = 96 elems over 64 lanes: lane + optional 64+lane)
  int wv = tid >> 6, lane = tid & 63;
  for (int r = wv; r < 24; r += 4) {
    float iq = iqv[r];
    float v0 = Sl[r][lane] * iq * ik[lane];
    float v1 = (lane < 32) ? Sl[r][64 + lane] * iq * ik[64 + lane] : -1e30f;
    float mx = fmaxf(v0, v1);
#pragma unroll
    for (int off = 32; off; off >>= 1) mx = fmaxf(mx, __shfl_xor(mx, off, 64));
    float e0 = __expf(v0 - mx);
    float e1 = (lane < 32) ? __expf(v1 - mx) : 0.f;
    float sm = e0 + e1;
#pragma unroll
    for (int off = 32; off; off >>= 1) sm += __shfl_xor(sm, off, 64);
    float inv = 1.0f / sm;
    unsigned short* row = attnB + (size_t)bh * 9984 + (base + r) * 104;
    row[lane] = f2b(e0 * inv);
    if (lane < 32) row[64 + lane] = f2b(e1 * inv);
    else if (64 + lane < 104) row[64 + lane] = 0;   // pad cols 96..103
  }
}

// ---------------- out = attn @ v (attn pre-softmaxed) ----------------
__global__ __launch_bounds__(256, 4) void attn_v(
    const unsigned short* __restrict__ attnB, const unsigned short* __restrict__ vT,
    unsigned short* __restrict__ U) {
  // attn [96][104]@0 (padded dest region 10240), vs [128][13 chunks][8]@10240 (13312)
  __shared__ __align__(16) unsigned short lds[23552];
  int blk = blockIdx.x;
  int bh = blk >> 5, nc = blk & 31;
  int b = bh >> 3, h = bh & 7;
  int n0 = nc * 128;
  int tid = threadIdx.x, wid = tid >> 6, lane = tid & 63;
  int wm = wid >> 1, wn = wid & 1, quad = lane >> 4, l16 = lane & 15;

  // stage attn [96][104]: 1248 16B chunks, contiguous in global AND lds (stride 104 = 13 chunks).
  const unsigned short* ab = attnB + (size_t)bh * 9984;
#pragma unroll
  for (int i = 0; i < 5; i++) {
    int id = i * 256 + tid;
    int ids = id < 1248 ? id : 1247;
    gload16(ab + (size_t)ids * 8, &lds[(i * 4 + wid) * 512]);
  }

  // stage v chunk [128 n][96 e] -> [row][13 chunks] (13*16B = 208B row, 2-way banks)
  const unsigned short* vb = vT + (size_t)bh * 4096 * 96 + (size_t)n0 * 96;
#pragma unroll
  for (int i = 0; i < 7; i++) {
    int ig = wid + i * 4;                   // 0..27
    if (ig < 26) {
      int id = ig * 64 + lane;              // slot = row*13 + chunk
      int row = id / 13;
      int ch = id - row * 13;
      if (ch > 11) ch = 11;                 // pad slot: load harmless dup
      gload16(vb + (size_t)row * 96 + ch * 8, &lds[10240 + ig * 512]);
    }
  }
  __syncthreads();

  f32x4 acc[3][4];
  f32x4 z = {0.f, 0.f, 0.f, 0.f};
#pragma unroll
  for (int i = 0; i < 3; i++)
#pragma unroll
    for (int j = 0; j < 4; j++) acc[i][j] = z;
#pragma unroll
  for (int et = 0; et < 3; et++) {
    bf16x8 af[3], bfr[4];
#pragma unroll
    for (int mi = 0; mi < 3; mi++)
      af[mi] = *(const bf16x8*)&lds[(wm * 48 + mi * 16 + l16) * 104 + (et * 4 + quad) * 8];
#pragma unroll
    for (int ni = 0; ni < 4; ni++)
      bfr[ni] = *(const bf16x8*)&lds[10240 + (wn * 64 + ni * 16 + l16) * 104 + (et * 4 + quad) * 8];
#pragma unroll
    for (int mi = 0; mi < 3; mi++)
#pragma unroll
      for (int ni = 0; ni < 4; ni++)
        acc[mi][ni] = __builtin_amdgcn_mfma_f32_16x16x32_bf16(af[mi], bfr[ni], acc[mi][ni], 0, 0, 0);
  }
  __syncthreads();

  // bounce [128 n][104] then coalesced U writes
#pragma unroll
  for (int mi = 0; mi < 3; mi++)
#pragma unroll
    for (int ni = 0; ni < 4; ni++)
#pragma unroll
      for (int r = 0; r < 4; r++) {
        int d = wm * 48 + mi * 16 + quad * 4 + r;
        int n = wn * 64 + ni * 16 + l16;
        lds[n * 104 + d] = f2b(acc[mi][ni][r]);
      }
  __syncthreads();
#pragma unroll
  for (int it = 0; it < 6; it++) {
    int id = tid + it * 256;                // 128 n x 12 chunks
    int nr = id / 12, ch = id - nr * 12;
    *(uint4*)&U[((size_t)(b * 4096 + n0 + nr)) * 768 + h * 96 + ch * 8] =
        *(const uint4*)&lds[nr * 104 + ch * 8];
  }
}

// ---------------- GEMM3: y = U @ Wproj + bproj ----------------
__global__ __launch_bounds__(256, 2) void gemm_out(
    const unsigned short* __restrict__ A, const unsigned short* __restrict__ Bt,
    const float* __restrict__ bias, float* __restrict__ out) {
  __shared__ __align__(16) unsigned short lds[16384];
  int bj = blockIdx.x;                      // 0..5
  int bm = blockIdx.y;                      // 0..255
  int m0 = bm * 128, j0 = bj * 128;
  int tid = threadIdx.x;
  int wid = tid >> 6, lane = tid & 63;
  int wm = wid >> 1, wn = wid & 1;
  int quad = lane >> 4, l16 = lane & 15;
  int srow = lane >> 3, sch = lane & 7;
  int cmem = sch ^ srow;

  f32x4 acc[4][4];
  f32x4 z = {0.f, 0.f, 0.f, 0.f};
#pragma unroll
  for (int i = 0; i < 4; i++)
#pragma unroll
    for (int j = 0; j < 4; j++) acc[i][j] = z;

  const unsigned short* Ab = A + (size_t)m0 * 768;
  const unsigned short* Bb = Bt + (size_t)j0 * 768;

  for (int k0 = 0; k0 < 768; k0 += 64) {
#pragma unroll
    for (int i = 0; i < 4; i++) {
      int ig = wid * 4 + i;
      int row = ig * 8 + srow;
      gload16(Ab + (size_t)row * 768 + k0 + cmem * 8, &lds[ig * 512]);
      gload16(Bb + (size_t)row * 768 + k0 + cmem * 8, &lds[8192 + ig * 512]);
    }
    __syncthreads();
#pragma unroll
    for (int kk = 0; kk < 2; kk++) {
      int cs = ((kk * 4 + quad) ^ (l16 & 7)) * 8;
      bf16x8 af[4], bfr[4];
#pragma unroll
      for (int mi = 0; mi < 4; mi++)
        af[mi] = *(const bf16x8*)&lds[(wm * 64 + mi * 16 + l16) * 64 + cs];
#pragma unroll
      for (int ni = 0; ni < 4; ni++)
        bfr[ni] = *(const bf16x8*)&lds[8192 + (wn * 64 + ni * 16 + l16) * 64 + cs];
#pragma unroll
      for (int mi = 0; mi < 4; mi++)
#pragma unroll
        for (int ni = 0; ni < 4; ni++)
          acc[mi][ni] = __builtin_amdgcn_mfma_f32_16x16x32_bf16(af[mi], bfr[ni], acc[mi][ni], 0, 0, 0);
    }
    __syncthreads();
  }
#pragma unroll
  for (int ni = 0; ni < 4; ni++) {
    int ccol = j0 + wn * 64 + ni * 16 + l16;
    float bv = bias[ccol];
#pragma unroll
    for (int mi = 0; mi < 4; mi++)
#pragma unroll
      for (int r = 0; r < 4; r++)
        out[(size_t)(m0 + wm * 64 + mi * 16 + quad * 4 + r) * 768 + ccol] = acc[mi][ni][r] + bv;
  }
}

// ---------------- host ----------------
extern "C" void kernel_launch(void* const* d_in, const int* in_sizes, int n_in,
                              void* d_out, int out_size, void* d_ws, size_t ws_size,
                              hipStream_t stream) {
  const float* x = (const float*)d_in[0];
  const float* Wqkv = (const float*)d_in[1];
  const float* temp = (const float*)d_in[2];
  const float* Wproj = (const float*)d_in[3];
  const float* bproj = (const float*)d_in[4];
  float* out = (float*)d_out;
  char* ws = (char*)d_ws;

  unsigned short* xb     = (unsigned short*)(ws);                 // 50331648 B
  unsigned short* WqkvT  = (unsigned short*)(ws + 50331648);      // 3538944
  unsigned short* WprojT = (unsigned short*)(ws + 53870592);      // 1179648
  unsigned short* qkT    = (unsigned short*)(ws + 55050240);      // 100663296
  unsigned short* vT     = (unsigned short*)(ws + 155713536);     // 50331648
  unsigned short* U      = (unsigned short*)(ws + 206045184);     // 50331648
  float* normsq          = (float*)(ws + 258736128);              // 49152
  // S8 partials [8][64][96][96] f32 = 18874368 B, aliases xb (dead after gemm_qkv)
  float* S8              = (float*)(ws);
  // attnB aliases qkT (dead after attn_s): [64][96][104] bf16 = 1277952 B
  unsigned short* attnB  = qkT;

  cvt_bf16<<<dim3(4096), dim3(256), 0, stream>>>(x, xb, 25165824 / 4, normsq, 3072);
  cvt_transpose<<<dim3(72, 24), dim3(256), 0, stream>>>(Wqkv, WqkvT, 768, 2304);
  cvt_transpose<<<dim3(24, 24), dim3(256), 0, stream>>>(Wproj, WprojT, 768, 768);
  gemm_qkv<<<dim3(9, 128), dim3(512), 0, stream>>>(xb, WqkvT, qkT, vT, normsq);
  attn_s<<<dim3(512), dim3(256), 0, stream>>>(qkT, S8);
  softmax96<<<dim3(4, 64), dim3(256), 0, stream>>>(S8, normsq, temp, attnB);
  attn_v<<<dim3(2048), dim3(256), 0, stream>>>(attnB, vT, U);
  gemm_out<<<dim3(6, 256), dim3(256), 0, stream>>>(U, WprojT, bproj, out);
}